// Round 1
// baseline (1365.158 us; speedup 1.0000x reference)
//
#include <hip/hip_runtime.h>
#include <hip/hip_bf16.h>
#include <math.h>

typedef unsigned short u16;
typedef __attribute__((ext_vector_type(8))) short short8;   // 8 bf16 (4 VGPRs) MFMA A/B frag
typedef __attribute__((ext_vector_type(4))) short short4v;  // 4 bf16 packed store
typedef __attribute__((ext_vector_type(4))) float f32x4;    // MFMA C/D frag

#define MFMA(a,b,c) __builtin_amdgcn_mfma_f32_16x16x32_bf16(a,b,c,0,0,0)

// ---- config ----
#define LTOK   138240      // 8*96*180
#define DIM    192
#define NLON_  15
#define NW_    64
#define NTOK_  144
// windowed row r = (lon*64 + w)*144 + n

__device__ __forceinline__ float bf2f(u16 u){ unsigned v=((unsigned)u)<<16; float f; __builtin_memcpy(&f,&v,4); return f; }
__device__ __forceinline__ u16 f2bf(float f){ unsigned v; __builtin_memcpy(&v,&f,4); v = v + 0x7fffu + ((v>>16)&1u); return (u16)(v>>16); }

// windowed row -> original token index (handles roll(+1,+3,+6) inverse mapping)
__device__ __forceinline__ int win_to_tok(int r){
  int lon = r/9216; int rem = r - lon*9216;      // 9216 = 64*144
  int w = rem/144, n = rem - w*144;
  int ip=w>>4, il=w&15;
  int wp=n/72, t=n-wp*72, wl=t/12, ww=t-wl*12;
  int p=ip*2+wp, la=il*6+wl, lo=lon*12+ww;
  int p0=p+1;  if(p0>=8)   p0-=8;
  int la0=la+3; if(la0>=96) la0-=96;
  int lo0=lo+6; if(lo0>=180)lo0-=180;
  return (p0*96+la0)*180+lo0;
}

// ---------------- K1: LN1 + roll + window partition -> bf16 A ----------------
__global__ __launch_bounds__(256) void ln1_window_kernel(
    const float* __restrict__ x, const float* __restrict__ g, const float* __restrict__ b,
    u16* __restrict__ A)
{
  int r = blockIdx.x*4 + (threadIdx.x>>6);
  int lane = threadIdx.x & 63;
  size_t src = (size_t)win_to_tok(r)*DIM;
  float v0=x[src+lane], v1=x[src+64+lane], v2=x[src+128+lane];
  float s=v0+v1+v2;
  for(int m=32;m>=1;m>>=1) s += __shfl_xor(s,m);
  float mean = s*(1.f/192.f);
  float d0=v0-mean,d1=v1-mean,d2=v2-mean;
  float q=d0*d0+d1*d1+d2*d2;
  for(int m=32;m>=1;m>>=1) q += __shfl_xor(q,m);
  float rstd = rsqrtf(q*(1.f/192.f)+1e-5f);
  size_t o = (size_t)r*DIM;
  A[o+lane]     = f2bf(d0*rstd*g[lane]     + b[lane]);
  A[o+64+lane]  = f2bf(d1*rstd*g[64+lane]  + b[64+lane]);
  A[o+128+lane] = f2bf(d2*rstd*g[128+lane] + b[128+lane]);
}

// ---------------- K2: transpose fp32 [K][N] -> bf16 [N][K] ----------------
__global__ __launch_bounds__(256) void transpose_bf16_kernel(
    const float* __restrict__ src, u16* __restrict__ dst, int K, int N)
{
  int idx = blockIdx.x*256 + threadIdx.x;
  if (idx >= K*N) return;
  int k = idx / N, n = idx - k*N;
  dst[n*K + k] = f2bf(src[idx]);
}

// ---------------- K3: fused QKV + earth attention per (lon,w,head) ----------------
// 9 waves, wave i owns S row-tile [16i,16i+16). LDS: Ws(B-op weights), q/k/v, P.
#define SM_WS   0                  // [96][200] u16  = 38400 B
#define SM_QS   38400              // [144][40] u16  = 11520 B
#define SM_KS   49920              // [144][40] u16  = 11520 B
#define SM_VS   61440              // [32][168] u16  = 10752 B (v transposed, k-padded to 160)
#define SM_PS   72192              // [144][168] u16 = 48384 B (9 waves x 16 rows)
#define SM_T1   120576             // int[144]
#define SM_T2   121152             // int[144]
#define SM_RG   121728             // int[144]
#define SMEM3   122304

__global__ __launch_bounds__(576) void attn_kernel(
    const u16* __restrict__ A,      // windowed bf16 [138240][192]
    const u16* __restrict__ Wt,     // qkv_w_t bf16 [576][192]
    const float* __restrict__ qkvb, // [576]
    const float* __restrict__ eb,   // earth_bias [3312][64][6]
    u16* __restrict__ O)            // windowed attn out bf16 [138240][192]
{
  extern __shared__ char smem[];
  u16* Ws = (u16*)(smem + SM_WS);
  u16* qs = (u16*)(smem + SM_QS);
  u16* ks_= (u16*)(smem + SM_KS);
  u16* vs = (u16*)(smem + SM_VS);
  u16* Ps = (u16*)(smem + SM_PS);
  int* t1s = (int*)(smem + SM_T1);
  int* t2s = (int*)(smem + SM_T2);
  int* rgs = (int*)(smem + SM_RG);

  int bh = blockIdx.x;
  int h  = bh % 6;
  int w  = (bh/6) & 63;
  int lon= bh / 384;
  int tid = threadIdx.x, lane = tid & 63, wv = tid >> 6;

  { // stage per-head weight slice (B-operand layout [outcol][k]), rows: q|k|v x 32
    int rr = tid % 96, chunk = tid / 96;           // chunk 0..5 covers k in 32-col blocks
    int mat = rr >> 5, c = rr & 31;
    const u16* s = Wt + (size_t)(mat*192 + h*32 + c)*192 + chunk*32;
    u16* d = Ws + rr*200 + chunk*32;
    *(uint4*)(d)    = *(const uint4*)(s);
    *(uint4*)(d+8)  = *(const uint4*)(s+8);
    *(uint4*)(d+16) = *(const uint4*)(s+16);
    *(uint4*)(d+24) = *(const uint4*)(s+24);
  }
  if (tid < 144) { // separable bias index + mask region tables
    int n = tid;
    int wp=n/72, t=n-wp*72, wl=t/12, ww=t-wl*12;
    t1s[n] = wp*828 + wl*23 + ww;
    t2s[n] = 1656*wp + 138*wl - ww + 11;
    int ip = w>>4, il = w&15;
    int p = ip*2+wp, la = il*6+wl;
    int rp = (p<6)?0:((p<7)?1:2);
    int rl = (la<90)?0:((la<93)?1:2);
    rgs[n] = rp*3+rl;
  }
  if (tid < 512) { int c = tid>>4; vs[c*168 + 144 + (tid&15)] = 0; } // zero K-pad of v
  for (int j=0;j<4;j++){ int idx = tid + j*576; int row = idx>>4;
    if (row < 144) Ps[row*168 + 144 + (idx&15)] = 0; }               // zero K-pad of P
  __syncthreads();

  size_t winbase = (size_t)(lon*64 + w)*144;
  int r0 = wv*16;
  int l15 = lane & 15, lg = lane >> 4;

  // QKV: q,k,v[r0..r0+16) for this head
  short8 af[6];
  {
    const u16* arow = A + (winbase + r0 + l15)*DIM + 8*lg;
    #pragma unroll
    for (int k0=0;k0<6;k0++) af[k0] = *(const short8*)(arow + k0*32);
  }
  const float qscale = 0.17677669529663687f; // 1/sqrt(32)
  #pragma unroll
  for (int mat=0; mat<3; mat++) {
    #pragma unroll
    for (int ct=0; ct<2; ct++) {
      f32x4 acc = {0.f,0.f,0.f,0.f};
      const u16* wrow = Ws + (mat*32 + ct*16 + l15)*200 + 8*lg;
      #pragma unroll
      for (int k0=0;k0<6;k0++) acc = MFMA(af[k0], *(const short8*)(wrow + k0*32), acc);
      float bias = qkvb[mat*192 + h*32 + ct*16 + l15];
      int cc = ct*16 + l15, rb = r0 + 4*lg;
      if (mat==0) { for (int i=0;i<4;i++) qs[(rb+i)*40 + cc] = f2bf((acc[i]+bias)*qscale); }
      else if (mat==1) { for (int i=0;i<4;i++) ks_[(rb+i)*40 + cc] = f2bf(acc[i]+bias); }
      else {
        short4v pk; for (int i=0;i<4;i++) pk[i] = (short)f2bf(acc[i]+bias);
        *(short4v*)(vs + cc*168 + rb) = pk;   // v stored transposed [c][token]
      }
    }
  }
  __syncthreads();

  // S = q k^T  (rows r0..r0+16, all 144 cols)
  short8 aq = *(const short8*)(qs + (r0 + l15)*40 + 8*lg);
  f32x4 sa[9];
  #pragma unroll
  for (int ct=0; ct<9; ct++) {
    short8 bk = *(const short8*)(ks_ + (ct*16 + l15)*40 + 8*lg);
    f32x4 z = {0.f,0.f,0.f,0.f};
    sa[ct] = MFMA(aq, bk, z);
  }
  // + earth bias + shift mask
  int t1v[4], rg[4];
  #pragma unroll
  for (int i=0;i<4;i++){ int n = r0 + 4*lg + i; t1v[i]=t1s[n]; rg[i]=rgs[n]; }
  #pragma unroll
  for (int ct=0; ct<9; ct++) {
    int m = ct*16 + l15;
    int t2v = t2s[m], rgm = rgs[m];
    #pragma unroll
    for (int i=0;i<4;i++) {
      float bv = eb[(size_t)(t1v[i]+t2v)*384 + w*6 + h];
      sa[ct][i] += bv + ((rg[i]==rgm) ? 0.f : -100.f);
    }
  }
  // row softmax (rows live in 16-lane groups)
  float rmax[4], rsum[4];
  #pragma unroll
  for (int i=0;i<4;i++) rmax[i] = sa[0][i];
  #pragma unroll
  for (int ct=1; ct<9; ct++) for (int i=0;i<4;i++) rmax[i] = fmaxf(rmax[i], sa[ct][i]);
  #pragma unroll
  for (int i=0;i<4;i++){ for (int m=1;m<16;m<<=1) rmax[i] = fmaxf(rmax[i], __shfl_xor(rmax[i], m, 16)); rsum[i]=0.f; }
  #pragma unroll
  for (int ct=0; ct<9; ct++) for (int i=0;i<4;i++) { float e = __expf(sa[ct][i]-rmax[i]); sa[ct][i]=e; rsum[i]+=e; }
  #pragma unroll
  for (int i=0;i<4;i++){ for (int m=1;m<16;m<<=1) rsum[i] += __shfl_xor(rsum[i], m, 16); }
  // write P (bf16) into this wave's tile
  #pragma unroll
  for (int ct=0; ct<9; ct++) for (int i=0;i<4;i++)
    Ps[(r0 + 4*lg + i)*168 + ct*16 + l15] = f2bf(sa[ct][i]);

  float rinv[4];
  #pragma unroll
  for (int i=0;i<4;i++) rinv[i] = 1.f/rsum[i];

  // O = (P v) / rowsum
  #pragma unroll
  for (int ct=0; ct<2; ct++) {
    f32x4 acc = {0.f,0.f,0.f,0.f};
    const u16* pr = Ps + (r0 + l15)*168 + 8*lg;
    const u16* vr = vs + (ct*16 + l15)*168 + 8*lg;
    #pragma unroll
    for (int k0=0;k0<5;k0++) acc = MFMA(*(const short8*)(pr + k0*32), *(const short8*)(vr + k0*32), acc);
    u16* orow = O + (winbase + r0 + 4*lg)*DIM + h*32 + ct*16 + l15;
    for (int i=0;i<4;i++) orow[(size_t)i*DIM] = f2bf(acc[i]*rinv[i]);
  }
}

// ---------------- K4: proj + window reverse + residual -> x2 (fp32, in d_out) ----------------
__global__ __launch_bounds__(512) void proj_kernel(
    const u16* __restrict__ AT,   // windowed attn bf16 [138240][192]
    const u16* __restrict__ Pw,   // proj_w_t bf16 [192][192]
    const float* __restrict__ pb, const float* __restrict__ x, float* __restrict__ out)
{
  __shared__ u16 As[128*200];
  __shared__ int tokmap[128];
  int tid = threadIdx.x;
  size_t rbase = (size_t)blockIdx.x*128;
  for (int j=0;j<6;j++){
    int cid = j*512 + tid;                // 3072 16B chunks
    int row = cid/24, cc = (cid-row*24)*8;
    *(uint4*)(As + row*200 + cc) = *(const uint4*)(AT + (rbase+row)*DIM + cc);
  }
  if (tid < 128) tokmap[tid] = win_to_tok((int)rbase + tid);
  __syncthreads();

  int lane = tid&63, wv = tid>>6, r0 = wv*16;
  int l15 = lane&15, lg = lane>>4;
  short8 af[6];
  const u16* arow = As + (r0+l15)*200 + 8*lg;
  #pragma unroll
  for (int k0=0;k0<6;k0++) af[k0] = *(const short8*)(arow + k0*32);
  #pragma unroll
  for (int ct=0; ct<12; ct++) {
    f32x4 acc = {0.f,0.f,0.f,0.f};
    const u16* wrow = Pw + (size_t)(ct*16+l15)*192 + 8*lg;
    #pragma unroll
    for (int k0=0;k0<6;k0++) acc = MFMA(af[k0], *(const short8*)(wrow + k0*32), acc);
    int col = ct*16+l15;
    float bias = pb[col];
    for (int i=0;i<4;i++){
      int tok = tokmap[r0 + 4*lg + i];
      size_t o = (size_t)tok*DIM + col;
      out[o] = x[o] + acc[i] + bias;
    }
  }
}

// ---------------- K5a: LN2 (token order) ----------------
__global__ __launch_bounds__(256) void ln2_kernel(
    const float* __restrict__ x2, const float* __restrict__ g, const float* __restrict__ b,
    u16* __restrict__ Y)
{
  int r = blockIdx.x*4 + (threadIdx.x>>6);
  int lane = threadIdx.x & 63;
  size_t src = (size_t)r*DIM;
  float v0=x2[src+lane], v1=x2[src+64+lane], v2=x2[src+128+lane];
  float s=v0+v1+v2;
  for(int m=32;m>=1;m>>=1) s += __shfl_xor(s,m);
  float mean = s*(1.f/192.f);
  float d0=v0-mean,d1=v1-mean,d2=v2-mean;
  float q=d0*d0+d1*d1+d2*d2;
  for(int m=32;m>=1;m>>=1) q += __shfl_xor(q,m);
  float rstd = rsqrtf(q*(1.f/192.f)+1e-5f);
  Y[src+lane]     = f2bf(d0*rstd*g[lane]     + b[lane]);
  Y[src+64+lane]  = f2bf(d1*rstd*g[64+lane]  + b[64+lane]);
  Y[src+128+lane] = f2bf(d2*rstd*g[128+lane] + b[128+lane]);
}

// ---------------- K5b: fused MLP (fc1 + exact GELU + fc2) + final residual ----------------
#define SMEM5 (51200 + 34816)   // Ys[128][200] + Hs[128][136]
__global__ __launch_bounds__(512) void mlp_kernel(
    const u16* __restrict__ Y,   // ln2 out bf16 [138240][192]
    const u16* __restrict__ W1,  // fc1_t bf16 [768][192]
    const float* __restrict__ b1,
    const u16* __restrict__ W2,  // fc2_t bf16 [192][768]
    const float* __restrict__ b2,
    float* __restrict__ out)     // x2 in, final out
{
  extern __shared__ char smem[];
  u16* Ys = (u16*)smem;
  u16* Hs = (u16*)(smem + 51200);
  int tid = threadIdx.x;
  size_t rbase = (size_t)blockIdx.x*128;
  for (int j=0;j<6;j++){
    int cid = j*512 + tid;
    int row = cid/24, cc = (cid-row*24)*8;
    *(uint4*)(Ys + row*200 + cc) = *(const uint4*)(Y + (rbase+row)*DIM + cc);
  }
  __syncthreads();

  int lane = tid&63, wv = tid>>6, r0 = wv*16;
  int l15 = lane&15, lg = lane>>4;
  short8 af[6];
  const u16* yr = Ys + (r0+l15)*200 + 8*lg;
  #pragma unroll
  for (int k0=0;k0<6;k0++) af[k0] = *(const short8*)(yr + k0*32);

  f32x4 acc2[12];
  #pragma unroll
  for (int i=0;i<12;i++) acc2[i] = (f32x4){0.f,0.f,0.f,0.f};

  for (int ch=0; ch<6; ch++) {
    // fc1 chunk [128 cols] + GELU -> Hs (each wave owns its 16 rows; no barrier needed)
    #pragma unroll
    for (int ct=0; ct<8; ct++) {
      f32x4 a1 = {0.f,0.f,0.f,0.f};
      const u16* wr = W1 + (size_t)(ch*128 + ct*16 + l15)*192 + 8*lg;
      #pragma unroll
      for (int k0=0;k0<6;k0++) a1 = MFMA(af[k0], *(const short8*)(wr + k0*32), a1);
      float bb = b1[ch*128 + ct*16 + l15];
      for (int i=0;i<4;i++){
        float v = a1[i] + bb;
        float gl = 0.5f*v*(1.f + erff(v*0.70710678118654752f));
        Hs[(r0 + 4*lg + i)*136 + ct*16 + l15] = f2bf(gl);
      }
    }
    // fc2 partial accumulate
    #pragma unroll
    for (int k2=0; k2<4; k2++) {
      short8 ah = *(const short8*)(Hs + (r0+l15)*136 + k2*32 + 8*lg);
      #pragma unroll
      for (int ct2=0; ct2<12; ct2++) {
        const u16* wr2 = W2 + (size_t)(ct2*16+l15)*768 + ch*128 + k2*32 + 8*lg;
        acc2[ct2] = MFMA(ah, *(const short8*)(wr2), acc2[ct2]);
      }
    }
  }
  #pragma unroll
  for (int ct2=0; ct2<12; ct2++) {
    int col = ct2*16+l15;
    float bb = b2[col];
    for (int i=0;i<4;i++){
      size_t o = (rbase + r0 + 4*lg + i)*DIM + col;
      out[o] = out[o] + acc2[ct2][i] + bb;
    }
  }
}

// ---------------- launcher ----------------
extern "C" void kernel_launch(void* const* d_in, const int* in_sizes, int n_in,
                              void* d_out, int out_size, void* d_ws, size_t ws_size,
                              hipStream_t stream) {
  const float* x    = (const float*)d_in[0];
  const float* n1g  = (const float*)d_in[1];
  const float* n1b  = (const float*)d_in[2];
  const float* qkvw = (const float*)d_in[3];
  const float* qkvb = (const float*)d_in[4];
  const float* eb   = (const float*)d_in[5];
  const float* projw= (const float*)d_in[6];
  const float* projb= (const float*)d_in[7];
  const float* n2g  = (const float*)d_in[8];
  const float* n2b  = (const float*)d_in[9];
  const float* fc1w = (const float*)d_in[10];
  const float* fc1b = (const float*)d_in[11];
  const float* fc2w = (const float*)d_in[12];
  const float* fc2b = (const float*)d_in[13];
  float* out = (float*)d_out;
  char* ws = (char*)d_ws;

  u16* A   = (u16*)(ws);                 // 53,084,160 B (reused as LN2 output later)
  u16* AT  = (u16*)(ws + 53084160);      // 53,084,160 B
  u16* Wq  = (u16*)(ws + 106168320);     // qkv_w_t   221,184 B
  u16* Pw  = (u16*)(ws + 106389504);     // proj_w_t   73,728 B
  u16* W1  = (u16*)(ws + 106463232);     // fc1_t     294,912 B
  u16* W2  = (u16*)(ws + 106758144);     // fc2_t     294,912 B

  hipFuncSetAttribute((const void*)attn_kernel, hipFuncAttributeMaxDynamicSharedMemorySize, SMEM3);
  hipFuncSetAttribute((const void*)mlp_kernel,  hipFuncAttributeMaxDynamicSharedMemorySize, SMEM5);

  transpose_bf16_kernel<<<432, 256, 0, stream>>>(qkvw, Wq, 192, 576);
  transpose_bf16_kernel<<<144, 256, 0, stream>>>(projw, Pw, 192, 192);
  transpose_bf16_kernel<<<576, 256, 0, stream>>>(fc1w, W1, 192, 768);
  transpose_bf16_kernel<<<576, 256, 0, stream>>>(fc2w, W2, 768, 192);
  ln1_window_kernel<<<34560, 256, 0, stream>>>(x, n1g, n1b, A);
  attn_kernel<<<5760, 576, SMEM3, stream>>>(A, Wq, qkvb, eb, AT);
  proj_kernel<<<1080, 512, 0, stream>>>(AT, Pw, projb, x, out);
  ln2_kernel<<<34560, 256, 0, stream>>>(out, n2g, n2b, A);
  mlp_kernel<<<1080, 512, SMEM5, stream>>>(A, W1, fc1b, W2, fc2b, out);
}

// Round 2
// 657.497 us; speedup vs baseline: 2.0763x; 2.0763x over previous
//
#include <hip/hip_runtime.h>
#include <hip/hip_bf16.h>
#include <math.h>

typedef unsigned short u16;
typedef __attribute__((ext_vector_type(8))) short short8;   // 8 bf16 (4 VGPRs) MFMA A/B frag
typedef __attribute__((ext_vector_type(4))) short short4v;  // 4 bf16 packed store
typedef __attribute__((ext_vector_type(4))) float f32x4;    // MFMA C/D frag

#define MFMA(a,b,c) __builtin_amdgcn_mfma_f32_16x16x32_bf16(a,b,c,0,0,0)
#define DIM 192

__device__ __forceinline__ float bf2f(u16 u){ unsigned v=((unsigned)u)<<16; float f; __builtin_memcpy(&f,&v,4); return f; }
__device__ __forceinline__ u16 f2bf(float f){ unsigned v; __builtin_memcpy(&v,&f,4); v = v + 0x7fffu + ((v>>16)&1u); return (u16)(v>>16); }

// windowed row -> original token index (handles roll(+1,+3,+6) inverse mapping)
__device__ __forceinline__ int win_to_tok(int r){
  int lon = r/9216; int rem = r - lon*9216;      // 9216 = 64*144
  int w = rem/144, n = rem - w*144;
  int ip=w>>4, il=w&15;
  int wp=n/72, t=n-wp*72, wl=t/12, ww=t-wl*12;
  int p=ip*2+wp, la=il*6+wl, lo=lon*12+ww;
  int p0=p+1;  if(p0>=8)   p0-=8;
  int la0=la+3; if(la0>=96) la0-=96;
  int lo0=lo+6; if(lo0>=180)lo0-=180;
  return (p0*96+la0)*180+lo0;
}

// ---------------- K1: LN1 + roll + window partition -> bf16 A ----------------
__global__ __launch_bounds__(256) void ln1_window_kernel(
    const float* __restrict__ x, const float* __restrict__ g, const float* __restrict__ b,
    u16* __restrict__ A)
{
  int r = blockIdx.x*4 + (threadIdx.x>>6);
  int lane = threadIdx.x & 63;
  size_t src = (size_t)win_to_tok(r)*DIM;
  float v0=x[src+lane], v1=x[src+64+lane], v2=x[src+128+lane];
  float s=v0+v1+v2;
  for(int m=32;m>=1;m>>=1) s += __shfl_xor(s,m);
  float mean = s*(1.f/192.f);
  float d0=v0-mean,d1=v1-mean,d2=v2-mean;
  float q=d0*d0+d1*d1+d2*d2;
  for(int m=32;m>=1;m>>=1) q += __shfl_xor(q,m);
  float rstd = rsqrtf(q*(1.f/192.f)+1e-5f);
  size_t o = (size_t)r*DIM;
  A[o+lane]     = f2bf(d0*rstd*g[lane]     + b[lane]);
  A[o+64+lane]  = f2bf(d1*rstd*g[64+lane]  + b[64+lane]);
  A[o+128+lane] = f2bf(d2*rstd*g[128+lane] + b[128+lane]);
}

// ---------------- K2: transpose fp32 [K][N] -> bf16 [N][K] ----------------
__global__ __launch_bounds__(256) void transpose_bf16_kernel(
    const float* __restrict__ src, u16* __restrict__ dst, int K, int N)
{
  int idx = blockIdx.x*256 + threadIdx.x;
  if (idx >= K*N) return;
  int k = idx / N, n = idx - k*N;
  dst[n*K + k] = f2bf(src[idx]);
}

// ---------------- K2b: expand earth bias (+fold shift mask) -> Bexp[w*6+h][n][m] bf16 ----------------
__global__ __launch_bounds__(256) void bias_expand_kernel(
    const float* __restrict__ eb, u16* __restrict__ Bexp)
{
  __shared__ int t1s[144], t2s[144], rgs[144];
  int bid = blockIdx.x;           // bid = w*6 + h
  int w = bid / 6;
  int tid = threadIdx.x;
  if (tid < 144) {
    int n = tid;
    int wp=n/72, t=n-wp*72, wl=t/12, ww=t-wl*12;
    t1s[n] = wp*828 + wl*23 + ww;
    t2s[n] = 1656*wp + 138*wl - ww + 11;
    int ip = w>>4, il = w&15;
    int p = ip*2+wp, la = il*6+wl;
    int rp = (p<6)?0:((p<7)?1:2);
    int rl = (la<90)?0:((la<93)?1:2);
    rgs[n] = rp*3+rl;
  }
  __syncthreads();
  size_t ob = (size_t)bid*20736;
  for (int idx = tid; idx < 20736; idx += 256) {
    int n = idx/144, m = idx - n*144;
    float bv = eb[(size_t)(t1s[n]+t2s[m])*384 + bid];
    bv += (rgs[n]==rgs[m]) ? 0.f : -100.f;
    Bexp[ob + idx] = f2bf(bv);
  }
}

// ---------------- K3: fused QKV + earth attention per (lon,w,head) ----------------
#define SM_WS   0                  // [96][200] u16  = 38400 B
#define SM_QS   38400              // [144][40] u16  = 11520 B
#define SM_KS   49920              // [144][40] u16  = 11520 B
#define SM_VS   61440              // [32][168] u16  = 10752 B (v transposed, k-padded)
#define SM_PS   72192              // [144][168] u16 = 48384 B
#define SMEM3   120576

__global__ __launch_bounds__(576) void attn_kernel(
    const u16* __restrict__ A,      // windowed bf16 [138240][192]
    const u16* __restrict__ Wt,     // qkv_w_t bf16 [576][192]
    const float* __restrict__ qkvb, // [576]
    const u16* __restrict__ Bexp,   // [384][144][144] bf16 bias+mask
    u16* __restrict__ O)            // windowed attn out bf16 [138240][192]
{
  extern __shared__ char smem[];
  u16* Ws = (u16*)(smem + SM_WS);
  u16* qs = (u16*)(smem + SM_QS);
  u16* ks_= (u16*)(smem + SM_KS);
  u16* vs = (u16*)(smem + SM_VS);
  u16* Ps = (u16*)(smem + SM_PS);

  int bh = blockIdx.x;
  int h  = bh % 6;
  int w  = (bh/6) & 63;
  int lon= bh / 384;
  int tid = threadIdx.x, lane = tid & 63, wv = tid >> 6;

  { // stage per-head weight slice (B-operand layout [outcol][k]), rows: q|k|v x 32
    int rr = tid % 96, chunk = tid / 96;
    int mat = rr >> 5, c = rr & 31;
    const u16* s = Wt + (size_t)(mat*192 + h*32 + c)*192 + chunk*32;
    u16* d = Ws + rr*200 + chunk*32;
    *(uint4*)(d)    = *(const uint4*)(s);
    *(uint4*)(d+8)  = *(const uint4*)(s+8);
    *(uint4*)(d+16) = *(const uint4*)(s+16);
    *(uint4*)(d+24) = *(const uint4*)(s+24);
  }
  if (tid < 512) { int c = tid>>4; vs[c*168 + 144 + (tid&15)] = 0; } // zero K-pad of v
  for (int j=0;j<4;j++){ int idx = tid + j*576; int row = idx>>4;
    if (row < 144) Ps[row*168 + 144 + (idx&15)] = 0; }               // zero K-pad of P
  __syncthreads();

  size_t winbase = (size_t)(lon*64 + w)*144;
  int r0 = wv*16;
  int l15 = lane & 15, lg = lane >> 4;

  // QKV for rows r0..r0+16, this head
  short8 af[6];
  {
    const u16* arow = A + (winbase + r0 + l15)*DIM + 8*lg;
    #pragma unroll
    for (int k0=0;k0<6;k0++) af[k0] = *(const short8*)(arow + k0*32);
  }
  const float qscale = 0.17677669529663687f; // 1/sqrt(32)
  #pragma unroll
  for (int mat=0; mat<3; mat++) {
    #pragma unroll
    for (int ct=0; ct<2; ct++) {
      f32x4 acc = {0.f,0.f,0.f,0.f};
      const u16* wrow = Ws + (mat*32 + ct*16 + l15)*200 + 8*lg;
      #pragma unroll
      for (int k0=0;k0<6;k0++) acc = MFMA(af[k0], *(const short8*)(wrow + k0*32), acc);
      float bias = qkvb[mat*192 + h*32 + ct*16 + l15];
      int cc = ct*16 + l15, rb = r0 + 4*lg;
      if (mat==0) { for (int i=0;i<4;i++) qs[(rb+i)*40 + cc] = f2bf((acc[i]+bias)*qscale); }
      else if (mat==1) { for (int i=0;i<4;i++) ks_[(rb+i)*40 + cc] = f2bf(acc[i]+bias); }
      else {
        short4v pk; for (int i=0;i<4;i++) pk[i] = (short)f2bf(acc[i]+bias);
        *(short4v*)(vs + cc*168 + rb) = pk;   // v stored transposed [c][token]
      }
    }
  }
  __syncthreads();

  // S = q k^T
  short8 aq = *(const short8*)(qs + (r0 + l15)*40 + 8*lg);
  f32x4 sa[9];
  #pragma unroll
  for (int ct=0; ct<9; ct++) {
    short8 bk = *(const short8*)(ks_ + (ct*16 + l15)*40 + 8*lg);
    f32x4 z = {0.f,0.f,0.f,0.f};
    sa[ct] = MFMA(aq, bk, z);
  }
  // + expanded bias(+mask), coalesced bf16 reads
  {
    const u16* brow = Bexp + (size_t)(w*6+h)*20736 + (size_t)(r0 + 4*lg)*144;
    #pragma unroll
    for (int ct=0; ct<9; ct++) {
      int m = ct*16 + l15;
      #pragma unroll
      for (int i=0;i<4;i++) sa[ct][i] += bf2f(brow[i*144 + m]);
    }
  }
  // row softmax (rows live in 16-lane groups)
  float rmax[4], rsum[4];
  #pragma unroll
  for (int i=0;i<4;i++) rmax[i] = sa[0][i];
  #pragma unroll
  for (int ct=1; ct<9; ct++) for (int i=0;i<4;i++) rmax[i] = fmaxf(rmax[i], sa[ct][i]);
  #pragma unroll
  for (int i=0;i<4;i++){ for (int m=1;m<16;m<<=1) rmax[i] = fmaxf(rmax[i], __shfl_xor(rmax[i], m, 16)); rsum[i]=0.f; }
  #pragma unroll
  for (int ct=0; ct<9; ct++) for (int i=0;i<4;i++) { float e = __expf(sa[ct][i]-rmax[i]); sa[ct][i]=e; rsum[i]+=e; }
  #pragma unroll
  for (int i=0;i<4;i++){ for (int m=1;m<16;m<<=1) rsum[i] += __shfl_xor(rsum[i], m, 16); }
  #pragma unroll
  for (int ct=0; ct<9; ct++) for (int i=0;i<4;i++)
    Ps[(r0 + 4*lg + i)*168 + ct*16 + l15] = f2bf(sa[ct][i]);

  float rinv[4];
  #pragma unroll
  for (int i=0;i<4;i++) rinv[i] = 1.f/rsum[i];

  // O = (P v) / rowsum
  #pragma unroll
  for (int ct=0; ct<2; ct++) {
    f32x4 acc = {0.f,0.f,0.f,0.f};
    const u16* pr = Ps + (r0 + l15)*168 + 8*lg;
    const u16* vr = vs + (ct*16 + l15)*168 + 8*lg;
    #pragma unroll
    for (int k0=0;k0<5;k0++) acc = MFMA(*(const short8*)(pr + k0*32), *(const short8*)(vr + k0*32), acc);
    u16* orow = O + (winbase + r0 + 4*lg)*DIM + h*32 + ct*16 + l15;
    for (int i=0;i<4;i++) orow[(size_t)i*DIM] = f2bf(acc[i]*rinv[i]);
  }
}

// ---------------- K4: proj + window reverse + residual -> x2 (fp32, in d_out) ----------------
#define SMEMP (73728 + 512)
__global__ __launch_bounds__(512) void proj_kernel(
    const u16* __restrict__ AT,   // windowed attn bf16 [138240][192]
    const u16* __restrict__ Pw,   // proj_w_t bf16 [192][192] (natural)
    const float* __restrict__ pb, const float* __restrict__ x, float* __restrict__ out)
{
  extern __shared__ char smem[];
  u16* Pws = (u16*)smem;                  // swizzled [192][192]
  int* tokmap = (int*)(smem + 73728);
  int tid = threadIdx.x;
  size_t rbase = (size_t)blockIdx.x*128;
  #pragma unroll
  for (int j=0;j<9;j++){                  // 4608 granules of 16B
    int g = j*512 + tid;
    int row = g/24, jj = g - row*24;
    uint4 t = *(const uint4*)(Pw + (size_t)row*192 + jj*8);
    *(uint4*)(Pws + row*192 + ((jj ^ (row&7))*8)) = t;
  }
  if (tid < 128) tokmap[tid] = win_to_tok((int)rbase + tid);
  __syncthreads();

  int lane = tid&63, wv = tid>>6, r0 = wv*16;
  int l15 = lane&15, lg = lane>>4;
  short8 af[6];
  const u16* arow = AT + (rbase + r0 + l15)*DIM + 8*lg;
  #pragma unroll
  for (int k0=0;k0<6;k0++) af[k0] = *(const short8*)(arow + k0*32);
  #pragma unroll
  for (int ct=0; ct<12; ct++) {
    f32x4 acc = {0.f,0.f,0.f,0.f};
    const u16* wr = Pws + (ct*16+l15)*192;
    #pragma unroll
    for (int k0=0;k0<6;k0++) acc = MFMA(af[k0], *(const short8*)(wr + (((k0*4+lg)^(l15&7))*8)), acc);
    int col = ct*16+l15;
    float bias = pb[col];
    for (int i=0;i<4;i++){
      int tok = tokmap[r0 + 4*lg + i];
      size_t o = (size_t)tok*DIM + col;
      out[o] = x[o] + acc[i] + bias;
    }
  }
}

// ---------------- K5a: LN2 (token order) ----------------
__global__ __launch_bounds__(256) void ln2_kernel(
    const float* __restrict__ x2, const float* __restrict__ g, const float* __restrict__ b,
    u16* __restrict__ Y)
{
  int r = blockIdx.x*4 + (threadIdx.x>>6);
  int lane = threadIdx.x & 63;
  size_t src = (size_t)r*DIM;
  float v0=x2[src+lane], v1=x2[src+64+lane], v2=x2[src+128+lane];
  float s=v0+v1+v2;
  for(int m=32;m>=1;m>>=1) s += __shfl_xor(s,m);
  float mean = s*(1.f/192.f);
  float d0=v0-mean,d1=v1-mean,d2=v2-mean;
  float q=d0*d0+d1*d1+d2*d2;
  for(int m=32;m>=1;m>>=1) q += __shfl_xor(q,m);
  float rstd = rsqrtf(q*(1.f/192.f)+1e-5f);
  Y[src+lane]     = f2bf(d0*rstd*g[lane]     + b[lane]);
  Y[src+64+lane]  = f2bf(d1*rstd*g[64+lane]  + b[64+lane]);
  Y[src+128+lane] = f2bf(d2*rstd*g[128+lane] + b[128+lane]);
}

// ---------------- K5b: fused MLP (fc1 + tanh-GELU + fc2) + final residual ----------------
// LDS: W1s[128 cols][192 k] 48K | W2s[192 cols][128 k] 48K | Hs[128][136] 34K ; Ys aliases W1s
#define SMEM5 133120
__global__ __launch_bounds__(512) void mlp_kernel(
    const u16* __restrict__ Y,   // ln2 out bf16 [138240][192]
    const u16* __restrict__ W1,  // fc1_t bf16 [768][192] natural
    const float* __restrict__ b1,
    const u16* __restrict__ W2,  // fc2_t bf16 [192][768] natural
    const float* __restrict__ b2,
    float* __restrict__ out)     // x2 in, final out
{
  extern __shared__ char smem[];
  u16* W1s = (u16*)smem;
  u16* W2s = (u16*)(smem + 49152);
  u16* Hs  = (u16*)(smem + 98304);
  u16* Ys  = (u16*)smem;          // alias (dead after af load)
  int tid = threadIdx.x;
  size_t rbase = (size_t)blockIdx.x*128;

  { // stage Y tile: fully contiguous 48KB
    const u16* ysrc = Y + rbase*DIM;
    #pragma unroll
    for (int j=0;j<6;j++){
      int g = j*512 + tid;
      *(uint4*)(Ys + g*8) = *(const uint4*)(ysrc + g*8);
    }
  }
  __syncthreads();
  int lane = tid&63, wv = tid>>6, r0 = wv*16;
  int l15 = lane&15, lg = lane>>4;
  short8 af[6];
  #pragma unroll
  for (int k0=0;k0<6;k0++) af[k0] = *(const short8*)(Ys + (r0+l15)*192 + k0*32 + 8*lg);
  __syncthreads();   // Ys dead; W1s may overwrite

  f32x4 acc2[12];
  #pragma unroll
  for (int i=0;i<12;i++) acc2[i] = (f32x4){0.f,0.f,0.f,0.f};

  for (int ch=0; ch<6; ch++) {
    // stage W1 chunk (128 outcols x 192k), swizzled granules
    #pragma unroll
    for (int j=0;j<6;j++){
      int g = j*512 + tid;
      int row = g/24, jj = g - row*24;
      uint4 t = *(const uint4*)(W1 + ((size_t)(ch*128+row))*192 + jj*8);
      *(uint4*)(W1s + row*192 + ((jj ^ (row&7))*8)) = t;
    }
    // stage W2 chunk (192 outcols x 128k), swizzled granules
    #pragma unroll
    for (int j=0;j<6;j++){
      int g = j*512 + tid;
      int row = g>>4, jj = g&15;
      uint4 t = *(const uint4*)(W2 + (size_t)row*768 + ch*128 + jj*8);
      *(uint4*)(W2s + row*128 + ((jj ^ (row&7))*8)) = t;
    }
    __syncthreads();
    // fc1 chunk + GELU -> Hs (each wave owns its rows)
    #pragma unroll
    for (int ct=0; ct<8; ct++) {
      f32x4 a1 = {0.f,0.f,0.f,0.f};
      const u16* wr = W1s + (ct*16+l15)*192;
      #pragma unroll
      for (int k0=0;k0<6;k0++) a1 = MFMA(af[k0], *(const short8*)(wr + (((k0*4+lg)^(l15&7))*8)), a1);
      float bb = b1[ch*128 + ct*16 + l15];
      for (int i=0;i<4;i++){
        float v = a1[i] + bb;
        float u = v*(0.79788456080286536f + 0.03567740813636141f*v*v);
        float e = __expf(2.f*u);
        float th = 1.f - 2.f/(e + 1.f);
        Hs[(r0 + 4*lg + i)*136 + ct*16 + l15] = f2bf(0.5f*v*(1.f + th));
      }
    }
    // fc2 partial accumulate (B from LDS)
    #pragma unroll
    for (int k2=0; k2<4; k2++) {
      short8 ah = *(const short8*)(Hs + (r0+l15)*136 + k2*32 + 8*lg);
      #pragma unroll
      for (int ct2=0; ct2<12; ct2++) {
        const u16* wr2 = W2s + (ct2*16+l15)*128 + (((k2*4+lg)^(l15&7))*8);
        acc2[ct2] = MFMA(ah, *(const short8*)(wr2), acc2[ct2]);
      }
    }
    __syncthreads();   // before next stage overwrites W1s/W2s
  }
  #pragma unroll
  for (int ct2=0; ct2<12; ct2++) {
    int col = ct2*16+l15;
    float bb = b2[col];
    for (int i=0;i<4;i++){
      size_t o = (rbase + r0 + 4*lg + i)*DIM + col;
      out[o] = out[o] + acc2[ct2][i] + bb;
    }
  }
}

// ---------------- launcher ----------------
extern "C" void kernel_launch(void* const* d_in, const int* in_sizes, int n_in,
                              void* d_out, int out_size, void* d_ws, size_t ws_size,
                              hipStream_t stream) {
  const float* x    = (const float*)d_in[0];
  const float* n1g  = (const float*)d_in[1];
  const float* n1b  = (const float*)d_in[2];
  const float* qkvw = (const float*)d_in[3];
  const float* qkvb = (const float*)d_in[4];
  const float* eb   = (const float*)d_in[5];
  const float* projw= (const float*)d_in[6];
  const float* projb= (const float*)d_in[7];
  const float* n2g  = (const float*)d_in[8];
  const float* n2b  = (const float*)d_in[9];
  const float* fc1w = (const float*)d_in[10];
  const float* fc1b = (const float*)d_in[11];
  const float* fc2w = (const float*)d_in[12];
  const float* fc2b = (const float*)d_in[13];
  float* out = (float*)d_out;
  char* ws = (char*)d_ws;

  u16* A   = (u16*)(ws);                 // 53,084,160 B (reused as LN2 output later)
  u16* AT  = (u16*)(ws + 53084160);      // 53,084,160 B
  u16* Wq  = (u16*)(ws + 106168320);     // qkv_w_t   221,184 B
  u16* Pw  = (u16*)(ws + 106389504);     // proj_w_t   73,728 B
  u16* W1  = (u16*)(ws + 106463232);     // fc1_t     294,912 B
  u16* W2  = (u16*)(ws + 106758144);     // fc2_t     294,912 B
  // Bexp (15.9 MB bf16) parked in d_out — dead until proj_kernel overwrites it
  u16* Bexp = (u16*)d_out;

  hipFuncSetAttribute((const void*)attn_kernel, hipFuncAttributeMaxDynamicSharedMemorySize, SMEM3);
  hipFuncSetAttribute((const void*)proj_kernel, hipFuncAttributeMaxDynamicSharedMemorySize, SMEMP);
  hipFuncSetAttribute((const void*)mlp_kernel,  hipFuncAttributeMaxDynamicSharedMemorySize, SMEM5);

  transpose_bf16_kernel<<<432, 256, 0, stream>>>(qkvw, Wq, 192, 576);
  transpose_bf16_kernel<<<144, 256, 0, stream>>>(projw, Pw, 192, 192);
  transpose_bf16_kernel<<<576, 256, 0, stream>>>(fc1w, W1, 192, 768);
  transpose_bf16_kernel<<<576, 256, 0, stream>>>(fc2w, W2, 768, 192);
  bias_expand_kernel<<<384, 256, 0, stream>>>(eb, Bexp);
  ln1_window_kernel<<<34560, 256, 0, stream>>>(x, n1g, n1b, A);
  attn_kernel<<<5760, 576, SMEM3, stream>>>(A, Wq, qkvb, Bexp, AT);
  proj_kernel<<<1080, 512, SMEMP, stream>>>(AT, Pw, projb, x, out);
  ln2_kernel<<<34560, 256, 0, stream>>>(out, n2g, n2b, A);
  mlp_kernel<<<1080, 512, SMEM5, stream>>>(A, W1, fc1b, W2, fc2b, out);
}

// Round 3
// 529.279 us; speedup vs baseline: 2.5793x; 1.2423x over previous
//
#include <hip/hip_runtime.h>
#include <hip/hip_bf16.h>
#include <math.h>

typedef unsigned short u16;
typedef __attribute__((ext_vector_type(8))) short short8;   // 8 bf16 MFMA A/B frag
typedef __attribute__((ext_vector_type(4))) short short4v;  // 4 bf16 packed
typedef __attribute__((ext_vector_type(4))) float f32x4;    // MFMA C/D frag

#define MFMA(a,b,c) __builtin_amdgcn_mfma_f32_16x16x32_bf16(a,b,c,0,0,0)
#define DIM 192

__device__ __forceinline__ float bf2f(u16 u){ unsigned v=((unsigned)u)<<16; float f; __builtin_memcpy(&f,&v,4); return f; }
__device__ __forceinline__ u16 f2bf(float f){ unsigned v; __builtin_memcpy(&v,&f,4); v = v + 0x7fffu + ((v>>16)&1u); return (u16)(v>>16); }

__device__ __forceinline__ void gl_lds16(const u16* g, u16* l){
  __builtin_amdgcn_global_load_lds((const __attribute__((address_space(1))) unsigned int*)g,
                                   (__attribute__((address_space(3))) unsigned int*)l, 16, 0, 0);
}

// windowed row -> original token index (inverse of roll(-1,-3,-6) + partition)
__device__ __forceinline__ int win_to_tok(int r){
  int lon = r/9216; int rem = r - lon*9216;      // 9216 = 64*144
  int w = rem/144, n = rem - w*144;
  int ip=w>>4, il=w&15;
  int wp=n/72, t=n-wp*72, wl=t/12, ww=t-wl*12;
  int p=ip*2+wp, la=il*6+wl, lo=lon*12+ww;
  int p0=p+1;  if(p0>=8)   p0-=8;
  int la0=la+3; if(la0>=96) la0-=96;
  int lo0=lo+6; if(lo0>=180)lo0-=180;
  return (p0*96+la0)*180+lo0;
}

// ---------------- K1: LN1 + roll + window partition -> bf16 A ----------------
__global__ __launch_bounds__(256) void ln1_window_kernel(
    const float* __restrict__ x, const float* __restrict__ g, const float* __restrict__ b,
    u16* __restrict__ A)
{
  int r = blockIdx.x*4 + (threadIdx.x>>6);
  int lane = threadIdx.x & 63;
  size_t src = (size_t)win_to_tok(r)*DIM;
  float v0=x[src+lane], v1=x[src+64+lane], v2=x[src+128+lane];
  float s=v0+v1+v2;
  for(int m=32;m>=1;m>>=1) s += __shfl_xor(s,m);
  float mean = s*(1.f/192.f);
  float d0=v0-mean,d1=v1-mean,d2=v2-mean;
  float q=d0*d0+d1*d1+d2*d2;
  for(int m=32;m>=1;m>>=1) q += __shfl_xor(q,m);
  float rstd = rsqrtf(q*(1.f/192.f)+1e-5f);
  size_t o = (size_t)r*DIM;
  A[o+lane]     = f2bf(d0*rstd*g[lane]     + b[lane]);
  A[o+64+lane]  = f2bf(d1*rstd*g[64+lane]  + b[64+lane]);
  A[o+128+lane] = f2bf(d2*rstd*g[128+lane] + b[128+lane]);
}

// ---------------- K2: transpose fp32 [K][N] -> bf16 [N][K] (qkv_w, proj_w) ----------------
__global__ __launch_bounds__(256) void transpose_bf16_kernel(
    const float* __restrict__ src, u16* __restrict__ dst, int K, int N)
{
  int idx = blockIdx.x*256 + threadIdx.x;
  if (idx >= K*N) return;
  int k = idx / N, n = idx - k*N;
  dst[n*K + k] = f2bf(src[idx]);
}

// ---------------- K2b: preformat fc1 -> frag-major, XOR-swizzle baked ----------------
// W1f[ch 12][r 64][g 24][e 8]: = fc1w[k=(g^(r&7))*8+e][col=ch*64+r]
__global__ __launch_bounds__(256) void pf_w1_kernel(const float* __restrict__ fc1w, u16* __restrict__ W1f){
  int idx = blockIdx.x*256 + threadIdx.x;      // 147456 total
  int e = idx & 7, g3 = idx >> 3;
  int g = g3 % 24, r3 = g3 / 24;
  int r = r3 & 63, ch = r3 >> 6;
  int k = ((g ^ (r&7))<<3) + e;
  W1f[idx] = f2bf(fc1w[(size_t)k*768 + ch*64 + r]);
}
// W2f[ch 12][r 192][g 8][e 8]: = fc2w[k=ch*64+(g^(r&7))*8+e][col=r]
__global__ __launch_bounds__(256) void pf_w2_kernel(const float* __restrict__ fc2w, u16* __restrict__ W2f){
  int idx = blockIdx.x*256 + threadIdx.x;      // 147456 total
  int e = idx & 7, g3 = idx >> 3;
  int g = g3 & 7, r3 = g3 >> 3;
  int r = r3 % 192, ch = r3 / 192;
  int k = ch*64 + ((g ^ (r&7))<<3) + e;
  W2f[idx] = f2bf(fc2w[(size_t)k*192 + r]);
}

// ---------------- K2c: expand earth bias+mask -> lane-packed Bexp2 ----------------
// Bexp2[wh 384][rt 9][ct 9][lane 64][i 4] bf16
__global__ __launch_bounds__(256) void bias_expand_kernel(
    const float* __restrict__ eb, u16* __restrict__ B2)
{
  __shared__ int t1s[144], t2s[144], rgs[144];
  int bid = blockIdx.x;           // bid = w*6 + h
  int w = bid / 6;
  int tid = threadIdx.x;
  if (tid < 144) {
    int n = tid;
    int wp=n/72, t=n-wp*72, wl=t/12, ww=t-wl*12;
    t1s[n] = wp*828 + wl*23 + ww;
    t2s[n] = 1656*wp + 138*wl - ww + 11;
    int ip = w>>4, il = w&15;
    int p = ip*2+wp, la = il*6+wl;
    int rp = (p<6)?0:((p<7)?1:2);
    int rl = (la<90)?0:((la<93)?1:2);
    rgs[n] = rp*3+rl;
  }
  __syncthreads();
  size_t ob = (size_t)bid*20736;
  for (int idx = tid; idx < 20736; idx += 256) {
    int rt = idx/2304, rem = idx - rt*2304;
    int ct = rem >> 8, q = rem & 255;
    int lane = q >> 2, i = q & 3;
    int n = rt*16 + ((lane>>4)<<2) + i, m = ct*16 + (lane&15);
    float bv = eb[(size_t)(t1s[n]+t2s[m])*384 + bid];
    bv += (rgs[n]==rgs[m]) ? 0.f : -100.f;
    B2[ob + idx] = f2bf(bv);
  }
}

// ---------------- K3: fused QKV + earth attention per (lon,w,head) ----------------
#define SM_WS   0                  // [96][200] u16  = 38400 B
#define SM_QS   38400              // [144][40] u16  = 11520 B
#define SM_KS   49920              // [144][40] u16  = 11520 B
#define SM_VS   61440              // [32][168] u16  = 10752 B (v transposed, k-padded)
#define SM_PS   72192              // [144][168] u16 = 48384 B
#define SMEM3   120576

__global__ __launch_bounds__(576) void attn_kernel(
    const u16* __restrict__ A,      // windowed bf16 [138240][192]
    const u16* __restrict__ Wt,     // qkv_w_t bf16 [576][192]
    const float* __restrict__ qkvb, // [576]
    const u16* __restrict__ Bexp,   // lane-packed [384][9][9][64][4] bf16
    u16* __restrict__ O)            // windowed attn out bf16 [138240][192]
{
  extern __shared__ char smem[];
  u16* Ws = (u16*)(smem + SM_WS);
  u16* qs = (u16*)(smem + SM_QS);
  u16* ks_= (u16*)(smem + SM_KS);
  u16* vs = (u16*)(smem + SM_VS);
  u16* Ps = (u16*)(smem + SM_PS);

  int bh = blockIdx.x;
  int h  = bh % 6;
  int w  = (bh/6) & 63;
  int lon= bh / 384;
  int tid = threadIdx.x, lane = tid & 63, wv = tid >> 6;

  { // stage per-head weight slice (B-operand layout [outcol][k]), rows: q|k|v x 32
    int rr = tid % 96, chunk = tid / 96;
    int mat = rr >> 5, c = rr & 31;
    const u16* s = Wt + (size_t)(mat*192 + h*32 + c)*192 + chunk*32;
    u16* d = Ws + rr*200 + chunk*32;
    *(uint4*)(d)    = *(const uint4*)(s);
    *(uint4*)(d+8)  = *(const uint4*)(s+8);
    *(uint4*)(d+16) = *(const uint4*)(s+16);
    *(uint4*)(d+24) = *(const uint4*)(s+24);
  }
  if (tid < 512) { int c = tid>>4; vs[c*168 + 144 + (tid&15)] = 0; } // zero K-pad of v
  for (int j=0;j<4;j++){ int idx = tid + j*576; int row = idx>>4;
    if (row < 144) Ps[row*168 + 144 + (idx&15)] = 0; }               // zero K-pad of P
  __syncthreads();

  size_t winbase = (size_t)(lon*64 + w)*144;
  int r0 = wv*16;
  int l15 = lane & 15, lg = lane >> 4;

  // QKV for rows r0..r0+16, this head
  short8 af[6];
  {
    const u16* arow = A + (winbase + r0 + l15)*DIM + 8*lg;
    #pragma unroll
    for (int k0=0;k0<6;k0++) af[k0] = *(const short8*)(arow + k0*32);
  }
  const float qscale = 0.17677669529663687f; // 1/sqrt(32)
  #pragma unroll
  for (int mat=0; mat<3; mat++) {
    #pragma unroll
    for (int ct=0; ct<2; ct++) {
      f32x4 acc = {0.f,0.f,0.f,0.f};
      const u16* wrow = Ws + (mat*32 + ct*16 + l15)*200 + 8*lg;
      #pragma unroll
      for (int k0=0;k0<6;k0++) acc = MFMA(af[k0], *(const short8*)(wrow + k0*32), acc);
      float bias = qkvb[mat*192 + h*32 + ct*16 + l15];
      int cc = ct*16 + l15, rb = r0 + 4*lg;
      if (mat==0) { for (int i=0;i<4;i++) qs[(rb+i)*40 + cc] = f2bf((acc[i]+bias)*qscale); }
      else if (mat==1) { for (int i=0;i<4;i++) ks_[(rb+i)*40 + cc] = f2bf(acc[i]+bias); }
      else {
        short4v pk; for (int i=0;i<4;i++) pk[i] = (short)f2bf(acc[i]+bias);
        *(short4v*)(vs + cc*168 + rb) = pk;   // v stored transposed [c][token]
      }
    }
  }
  __syncthreads();

  // S = q k^T
  short8 aq = *(const short8*)(qs + (r0 + l15)*40 + 8*lg);
  f32x4 sa[9];
  #pragma unroll
  for (int ct=0; ct<9; ct++) {
    short8 bk = *(const short8*)(ks_ + (ct*16 + l15)*40 + 8*lg);
    f32x4 z = {0.f,0.f,0.f,0.f};
    sa[ct] = MFMA(aq, bk, z);
  }
  // + bias(+mask): one 8B coalesced load per tile
  {
    const u16* bb = Bexp + (((size_t)(w*6+h)*9 + wv)*9)*256 + lane*4;
    #pragma unroll
    for (int ct=0; ct<9; ct++) {
      short4v pk = *(const short4v*)(bb + ct*256);
      #pragma unroll
      for (int i=0;i<4;i++) sa[ct][i] += bf2f((u16)pk[i]);
    }
  }
  // row softmax (rows live in 16-lane groups)
  float rmax[4], rsum[4];
  #pragma unroll
  for (int i=0;i<4;i++) rmax[i] = sa[0][i];
  #pragma unroll
  for (int ct=1; ct<9; ct++) for (int i=0;i<4;i++) rmax[i] = fmaxf(rmax[i], sa[ct][i]);
  #pragma unroll
  for (int i=0;i<4;i++){ for (int m=1;m<16;m<<=1) rmax[i] = fmaxf(rmax[i], __shfl_xor(rmax[i], m, 16)); rsum[i]=0.f; }
  #pragma unroll
  for (int ct=0; ct<9; ct++) for (int i=0;i<4;i++) { float e = __expf(sa[ct][i]-rmax[i]); sa[ct][i]=e; rsum[i]+=e; }
  #pragma unroll
  for (int i=0;i<4;i++){ for (int m=1;m<16;m<<=1) rsum[i] += __shfl_xor(rsum[i], m, 16); }
  #pragma unroll
  for (int ct=0; ct<9; ct++) for (int i=0;i<4;i++)
    Ps[(r0 + 4*lg + i)*168 + ct*16 + l15] = f2bf(sa[ct][i]);

  float rinv[4];
  #pragma unroll
  for (int i=0;i<4;i++) rinv[i] = 1.f/rsum[i];

  // O = (P v) / rowsum
  #pragma unroll
  for (int ct=0; ct<2; ct++) {
    f32x4 acc = {0.f,0.f,0.f,0.f};
    const u16* pr = Ps + (r0 + l15)*168 + 8*lg;
    const u16* vr = vs + (ct*16 + l15)*168 + 8*lg;
    #pragma unroll
    for (int k0=0;k0<5;k0++) acc = MFMA(*(const short8*)(pr + k0*32), *(const short8*)(vr + k0*32), acc);
    u16* orow = O + (winbase + r0 + 4*lg)*DIM + h*32 + ct*16 + l15;
    for (int i=0;i<4;i++) orow[(size_t)i*DIM] = f2bf(acc[i]*rinv[i]);
  }
}

// ---------------- K4: proj + window reverse + residual + fused LN2 ----------------
#define SMEMP (73728 + 512)
__global__ __launch_bounds__(512, 4) void proj_ln2_kernel(
    const u16* __restrict__ AT,   // windowed attn bf16 [138240][192]
    const u16* __restrict__ Pw,   // proj_w_t bf16 [192][192]
    const float* __restrict__ pb, const float* __restrict__ x,
    const float* __restrict__ n2g, const float* __restrict__ n2b,
    float* __restrict__ out, u16* __restrict__ Y)
{
  extern __shared__ char smem[];
  u16* Pws = (u16*)smem;                  // swizzled [192][192]
  int* tokmap = (int*)(smem + 73728);
  int tid = threadIdx.x;
  size_t rbase = (size_t)blockIdx.x*128;
  #pragma unroll
  for (int j=0;j<9;j++){                  // 4608 granules of 16B
    int g = j*512 + tid;
    int row = g/24, jj = g - row*24;
    uint4 t = *(const uint4*)(Pw + (size_t)row*192 + jj*8);
    *(uint4*)(Pws + row*192 + ((jj ^ (row&7))*8)) = t;
  }
  if (tid < 128) tokmap[tid] = win_to_tok((int)rbase + tid);
  __syncthreads();

  int lane = tid&63, wv = tid>>6, r0 = wv*16;
  int l15 = lane&15, lg = lane>>4;
  short8 af[6];
  const u16* arow = AT + (rbase + r0 + l15)*DIM + 8*lg;
  #pragma unroll
  for (int k0=0;k0<6;k0++) af[k0] = *(const short8*)(arow + k0*32);

  f32x4 acc[12];
  #pragma unroll
  for (int ct=0; ct<12; ct++) {
    f32x4 a = {0.f,0.f,0.f,0.f};
    const u16* wr = Pws + (ct*16+l15)*192;
    #pragma unroll
    for (int k0=0;k0<6;k0++) a = MFMA(af[k0], *(const short8*)(wr + (((k0*4+lg)^(l15&7))*8)), a);
    acc[ct] = a;
  }
  int toks[4];
  #pragma unroll
  for (int i=0;i<4;i++) toks[i] = tokmap[r0 + 4*lg + i];
  // x2 = x + attn_proj + bias -> out; keep in regs for LN
  #pragma unroll
  for (int ct=0; ct<12; ct++) {
    int col = ct*16+l15;
    float bias = pb[col];
    #pragma unroll
    for (int i=0;i<4;i++){
      size_t o = (size_t)toks[i]*DIM + col;
      float v = x[o] + acc[ct][i] + bias;
      out[o] = v;
      acc[ct][i] = v;
    }
  }
  // fused LN2 over the 192 cols (12 regs x 16 lanes)
  float s[4] = {0,0,0,0};
  #pragma unroll
  for (int ct=0; ct<12; ct++) for (int i=0;i<4;i++) s[i] += acc[ct][i];
  #pragma unroll
  for (int i=0;i<4;i++){ for (int m=1;m<16;m<<=1) s[i] += __shfl_xor(s[i], m, 16); s[i] *= (1.f/192.f); }
  float q[4] = {0,0,0,0};
  #pragma unroll
  for (int ct=0; ct<12; ct++) for (int i=0;i<4;i++){ float d = acc[ct][i]-s[i]; q[i] += d*d; }
  #pragma unroll
  for (int i=0;i<4;i++){ for (int m=1;m<16;m<<=1) q[i] += __shfl_xor(q[i], m, 16); q[i] = rsqrtf(q[i]*(1.f/192.f)+1e-5f); }
  #pragma unroll
  for (int ct=0; ct<12; ct++) {
    int col = ct*16+l15;
    float gg = n2g[col], bb = n2b[col];
    #pragma unroll
    for (int i=0;i<4;i++)
      Y[(size_t)toks[i]*DIM + col] = f2bf((acc[ct][i]-s[i])*q[i]*gg + bb);
  }
}

// ---------------- K5: fused MLP, double-buffered async weight staging ----------------
// LDS: B0 [64][192] 24576 | B1 [192][64] 24576 | Hs [128][72] 18432 = 67584
#define SMEM5 67584
__global__ __launch_bounds__(512, 4) void mlp_kernel(
    const u16* __restrict__ Y,    // ln2 out bf16 [138240][192] (token order)
    const u16* __restrict__ W1f,  // [12][64][24][8]
    const float* __restrict__ b1,
    const u16* __restrict__ W2f,  // [12][192][8][8]
    const float* __restrict__ b2,
    float* __restrict__ out)
{
  extern __shared__ char smem[];
  u16* B0 = (u16*)smem;
  u16* B1 = (u16*)(smem + 24576);
  u16* Hs = (u16*)(smem + 49152);
  int tid = threadIdx.x;
  size_t rbase = (size_t)blockIdx.x*128;
  int lane = tid&63, wv = tid>>6, r0 = wv*16;
  int l15 = lane&15, lg = lane>>4;

  // A-frags direct from global (one-time)
  short8 af[6];
  {
    const u16* yrow = Y + (rbase + r0 + l15)*DIM + 8*lg;
    #pragma unroll
    for (int k0=0;k0<6;k0++) af[k0] = *(const short8*)(yrow + k0*32);
  }

  // prologue: stage W1 chunk 0 -> B0
  #pragma unroll
  for (int j=0;j<3;j++) gl_lds16(W1f + (size_t)tid*8 + j*4096, B0 + tid*8 + j*4096);
  __syncthreads();

  f32x4 acc2[12];
  #pragma unroll
  for (int i=0;i<12;i++) acc2[i] = (f32x4){0.f,0.f,0.f,0.f};

  for (int ch=0; ch<12; ch++) {
    // prefetch W2(ch) -> B1 (B1 free since last fc2's sync)
    {
      const u16* src = W2f + (size_t)ch*12288 + tid*8;
      #pragma unroll
      for (int j=0;j<3;j++) gl_lds16(src + j*4096, B1 + tid*8 + j*4096);
    }
    // fc1: 4 col tiles x 6 k, B from B0
    #pragma unroll
    for (int ct=0; ct<4; ct++) {
      f32x4 a1 = {0.f,0.f,0.f,0.f};
      const u16* wr = B0 + (ct*16+l15)*192;
      #pragma unroll
      for (int k0=0;k0<6;k0++) a1 = MFMA(af[k0], *(const short8*)(wr + (((k0*4+lg)^(l15&7))*8)), a1);
      float bb = b1[ch*64 + ct*16 + l15];
      #pragma unroll
      for (int i=0;i<4;i++){
        float v = a1[i] + bb;
        float u = v*(0.79788456080286536f + 0.03567740813636141f*v*v);
        float e = __expf(2.f*u);
        float th = 1.f - 2.f/(e + 1.f);
        Hs[(r0 + 4*lg + i)*72 + ct*16 + l15] = f2bf(0.5f*v*(1.f + th));
      }
    }
    __syncthreads();   // B1 staged complete; all waves done reading B0

    // prefetch W1(ch+1) -> B0
    if (ch < 11) {
      const u16* src = W1f + (size_t)(ch+1)*12288 + tid*8;
      #pragma unroll
      for (int j=0;j<3;j++) gl_lds16(src + j*4096, B0 + tid*8 + j*4096);
    }
    // fc2: A = Hs (own rows), B from B1; accumulate
    #pragma unroll
    for (int k2=0; k2<2; k2++) {
      short8 ah = *(const short8*)(Hs + (r0+l15)*72 + k2*32 + 8*lg);
      #pragma unroll
      for (int ct2=0; ct2<12; ct2++) {
        const u16* wr2 = B1 + (ct2*16+l15)*64 + (((k2*4+lg)^(l15&7))*8);
        acc2[ct2] = MFMA(ah, *(const short8*)(wr2), acc2[ct2]);
      }
    }
    __syncthreads();   // B0 staged complete; all waves done reading B1
  }
  #pragma unroll
  for (int ct2=0; ct2<12; ct2++) {
    int col = ct2*16+l15;
    float bb = b2[col];
    #pragma unroll
    for (int i=0;i<4;i++){
      size_t o = (rbase + r0 + 4*lg + i)*DIM + col;
      out[o] = out[o] + acc2[ct2][i] + bb;
    }
  }
}

// ---------------- launcher ----------------
extern "C" void kernel_launch(void* const* d_in, const int* in_sizes, int n_in,
                              void* d_out, int out_size, void* d_ws, size_t ws_size,
                              hipStream_t stream) {
  const float* x    = (const float*)d_in[0];
  const float* n1g  = (const float*)d_in[1];
  const float* n1b  = (const float*)d_in[2];
  const float* qkvw = (const float*)d_in[3];
  const float* qkvb = (const float*)d_in[4];
  const float* eb   = (const float*)d_in[5];
  const float* projw= (const float*)d_in[6];
  const float* projb= (const float*)d_in[7];
  const float* n2g  = (const float*)d_in[8];
  const float* n2b  = (const float*)d_in[9];
  const float* fc1w = (const float*)d_in[10];
  const float* fc1b = (const float*)d_in[11];
  const float* fc2w = (const float*)d_in[12];
  const float* fc2b = (const float*)d_in[13];
  float* out = (float*)d_out;
  char* ws = (char*)d_ws;

  u16* A   = (u16*)(ws);                 // 53,084,160 B  (LN1 out; later LN2 out Y)
  u16* AT  = (u16*)(ws + 53084160);      // 53,084,160 B
  u16* Wq  = (u16*)(ws + 106168320);     // qkv_w_t   221,184 B
  u16* Pw  = (u16*)(ws + 106389504);     // proj_w_t   73,728 B
  u16* W1f = (u16*)(ws + 106463232);     // fc1 frag-major 294,912 B
  u16* W2f = (u16*)(ws + 106758144);     // fc2 frag-major 294,912 B
  u16* Bexp = (u16*)d_out;               // 15.9 MB, dead once proj runs

  hipFuncSetAttribute((const void*)attn_kernel,     hipFuncAttributeMaxDynamicSharedMemorySize, SMEM3);
  hipFuncSetAttribute((const void*)proj_ln2_kernel, hipFuncAttributeMaxDynamicSharedMemorySize, SMEMP);
  hipFuncSetAttribute((const void*)mlp_kernel,      hipFuncAttributeMaxDynamicSharedMemorySize, SMEM5);

  transpose_bf16_kernel<<<432, 256, 0, stream>>>(qkvw, Wq, 192, 576);
  transpose_bf16_kernel<<<144, 256, 0, stream>>>(projw, Pw, 192, 192);
  pf_w1_kernel<<<576, 256, 0, stream>>>(fc1w, W1f);
  pf_w2_kernel<<<576, 256, 0, stream>>>(fc2w, W2f);
  bias_expand_kernel<<<384, 256, 0, stream>>>(eb, Bexp);
  ln1_window_kernel<<<34560, 256, 0, stream>>>(x, n1g, n1b, A);
  attn_kernel<<<5760, 576, SMEM3, stream>>>(A, Wq, qkvb, Bexp, AT);
  proj_ln2_kernel<<<1080, 512, SMEMP, stream>>>(AT, Pw, projb, x, n2g, n2b, out, A);
  mlp_kernel<<<1080, 512, SMEM5, stream>>>(A, W1f, fc1b, W2f, fc2b, out);
}

// Round 4
// 501.481 us; speedup vs baseline: 2.7223x; 1.0554x over previous
//
#include <hip/hip_runtime.h>
#include <hip/hip_bf16.h>
#include <math.h>

typedef unsigned short u16;
typedef __attribute__((ext_vector_type(8))) short short8;   // 8 bf16 MFMA A/B frag
typedef __attribute__((ext_vector_type(4))) short short4v;  // 4 bf16 packed
typedef __attribute__((ext_vector_type(4))) float f32x4;    // MFMA C/D frag

#define MFMA(a,b,c) __builtin_amdgcn_mfma_f32_16x16x32_bf16(a,b,c,0,0,0)
#define DIM 192

__device__ __forceinline__ float bf2f(u16 u){ unsigned v=((unsigned)u)<<16; float f; __builtin_memcpy(&f,&v,4); return f; }
__device__ __forceinline__ u16 f2bf(float f){ unsigned v; __builtin_memcpy(&v,&f,4); v = v + 0x7fffu + ((v>>16)&1u); return (u16)(v>>16); }

__device__ __forceinline__ void gl_lds16(const u16* g, u16* l){
  __builtin_amdgcn_global_load_lds((const __attribute__((address_space(1))) unsigned int*)g,
                                   (__attribute__((address_space(3))) unsigned int*)l, 16, 0, 0);
}

// windowed row -> original token index (inverse of roll(-1,-3,-6) + partition)
__device__ __forceinline__ int win_to_tok(int r){
  int lon = r/9216; int rem = r - lon*9216;      // 9216 = 64*144
  int w = rem/144, n = rem - w*144;
  int ip=w>>4, il=w&15;
  int wp=n/72, t=n-wp*72, wl=t/12, ww=t-wl*12;
  int p=ip*2+wp, la=il*6+wl, lo=lon*12+ww;
  int p0=p+1;  if(p0>=8)   p0-=8;
  int la0=la+3; if(la0>=96) la0-=96;
  int lo0=lo+6; if(lo0>=180)lo0-=180;
  return (p0*96+la0)*180+lo0;
}

// ---------------- K1: LN1 + roll + window partition -> bf16 A ----------------
__global__ __launch_bounds__(256) void ln1_window_kernel(
    const float* __restrict__ x, const float* __restrict__ g, const float* __restrict__ b,
    u16* __restrict__ A)
{
  int r = blockIdx.x*4 + (threadIdx.x>>6);
  int lane = threadIdx.x & 63;
  size_t src = (size_t)win_to_tok(r)*DIM;
  float v0=x[src+lane], v1=x[src+64+lane], v2=x[src+128+lane];
  float s=v0+v1+v2;
  for(int m=32;m>=1;m>>=1) s += __shfl_xor(s,m);
  float mean = s*(1.f/192.f);
  float d0=v0-mean,d1=v1-mean,d2=v2-mean;
  float q=d0*d0+d1*d1+d2*d2;
  for(int m=32;m>=1;m>>=1) q += __shfl_xor(q,m);
  float rstd = rsqrtf(q*(1.f/192.f)+1e-5f);
  size_t o = (size_t)r*DIM;
  A[o+lane]     = f2bf(d0*rstd*g[lane]     + b[lane]);
  A[o+64+lane]  = f2bf(d1*rstd*g[64+lane]  + b[64+lane]);
  A[o+128+lane] = f2bf(d2*rstd*g[128+lane] + b[128+lane]);
}

// ---------------- K2: transpose fp32 [K][N] -> bf16 [N][K] (qkv_w, proj_w) ----------------
__global__ __launch_bounds__(256) void transpose_bf16_kernel(
    const float* __restrict__ src, u16* __restrict__ dst, int K, int N)
{
  int idx = blockIdx.x*256 + threadIdx.x;
  if (idx >= K*N) return;
  int k = idx / N, n = idx - k*N;
  dst[n*K + k] = f2bf(src[idx]);
}

// ---------------- K2b: preformat fc1 -> frag-major, XOR-swizzle baked ----------------
// W1f[ch 12][r 64][g 24][e 8]: = fc1w[k=(g^(r&7))*8+e][col=ch*64+r]
__global__ __launch_bounds__(256) void pf_w1_kernel(const float* __restrict__ fc1w, u16* __restrict__ W1f){
  int idx = blockIdx.x*256 + threadIdx.x;      // 147456 total
  int e = idx & 7, g3 = idx >> 3;
  int g = g3 % 24, r3 = g3 / 24;
  int r = r3 & 63, ch = r3 >> 6;
  int k = ((g ^ (r&7))<<3) + e;
  W1f[idx] = f2bf(fc1w[(size_t)k*768 + ch*64 + r]);
}
// W2f[ch 12][r 192][g 8][e 8]: = fc2w[k=ch*64+(g^(r&7))*8+e][col=r]
__global__ __launch_bounds__(256) void pf_w2_kernel(const float* __restrict__ fc2w, u16* __restrict__ W2f){
  int idx = blockIdx.x*256 + threadIdx.x;      // 147456 total
  int e = idx & 7, g3 = idx >> 3;
  int g = g3 & 7, r3 = g3 >> 3;
  int r = r3 % 192, ch = r3 / 192;
  int k = ch*64 + ((g ^ (r&7))<<3) + e;
  W2f[idx] = f2bf(fc2w[(size_t)k*192 + r]);
}

// ---------------- K2c: expand earth bias+mask -> lane-packed Bexp ----------------
// Bexp[wh 384][nt 9][mt 9][lane 64][i 4] bf16:
//   value = bias[n = nt*16 + (lane&15)][m = mt*16 + ((lane>>4)<<2) + i]
__global__ __launch_bounds__(256) void bias_expand_kernel(
    const float* __restrict__ eb, u16* __restrict__ B2)
{
  __shared__ int t1s[144], t2s[144], rgs[144];
  int bid = blockIdx.x;           // bid = w*6 + h
  int w = bid / 6;
  int tid = threadIdx.x;
  if (tid < 144) {
    int n = tid;
    int wp=n/72, t=n-wp*72, wl=t/12, ww=t-wl*12;
    t1s[n] = wp*828 + wl*23 + ww;
    t2s[n] = 1656*wp + 138*wl - ww + 11;
    int ip = w>>4, il = w&15;
    int p = ip*2+wp, la = il*6+wl;
    int rp = (p<6)?0:((p<7)?1:2);
    int rl = (la<90)?0:((la<93)?1:2);
    rgs[n] = rp*3+rl;
  }
  __syncthreads();
  size_t ob = (size_t)bid*20736;
  for (int idx = tid; idx < 20736; idx += 256) {
    int i = idx & 3, lane = (idx>>2)&63, t = idx>>8;   // t = nt*9+mt
    int mt = t%9, nt = t/9;
    int n = nt*16 + (lane&15);
    int m = mt*16 + ((lane>>4)<<2) + i;
    float bv = eb[(size_t)(t1s[n]+t2s[m])*384 + bid];
    bv += (rgs[n]==rgs[m]) ? 0.f : -100.f;
    B2[ob + idx] = f2bf(bv);
  }
}

// ---------------- K3: fused QKV + earth attention per (lon,w,head) ----------------
// S^T / O^T operand-swapped MFMA structure: per-lane register softmax, packed LDS IO.
#define SM_WS   0                  // [96][200] u16  = 38400 B
#define SM_QS   38400              // [144][40] u16  = 11520 B
#define SM_KS   49920              // [144][40] u16  = 11520 B
#define SM_VS   61440              // [32][168] u16  = 10752 B (v transposed, k-padded)
#define SM_PS   72192              // [144][168] u16 = 48384 B ([n][m], m-padded)
#define SMEM3   120576

__global__ __launch_bounds__(576) void attn_kernel(
    const u16* __restrict__ A,      // windowed bf16 [138240][192]
    const u16* __restrict__ Wt,     // qkv_w_t bf16 [576][192]
    const float* __restrict__ qkvb, // [576]
    const u16* __restrict__ Bexp,   // lane-packed [384][9][9][64][4] bf16
    u16* __restrict__ O)            // windowed attn out bf16 [138240][192]
{
  extern __shared__ char smem[];
  u16* Ws = (u16*)(smem + SM_WS);
  u16* qs = (u16*)(smem + SM_QS);
  u16* ks_= (u16*)(smem + SM_KS);
  u16* vs = (u16*)(smem + SM_VS);
  u16* Ps = (u16*)(smem + SM_PS);

  // XCD-aware remap: same (w,h) for all 15 lon -> same XCD, consecutive; h inner within w.
  int bid = blockIdx.x;
  int logical = (bid & 7)*720 + (bid >> 3);     // 5760 = 8*720, bijective
  int lon = logical % 15;
  int wh  = logical / 15;                        // = w*6 + h
  int h = wh % 6, w = wh / 6;
  int tid = threadIdx.x, lane = tid & 63, wv = tid >> 6;

  { // stage per-head weight slice (rows: q|k|v x 32 outcols, [outcol][k])
    int rr = tid % 96, chunk = tid / 96;
    int mat = rr >> 5, c = rr & 31;
    const u16* s = Wt + (size_t)(mat*192 + h*32 + c)*192 + chunk*32;
    u16* d = Ws + rr*200 + chunk*32;
    *(uint4*)(d)    = *(const uint4*)(s);
    *(uint4*)(d+8)  = *(const uint4*)(s+8);
    *(uint4*)(d+16) = *(const uint4*)(s+16);
    *(uint4*)(d+24) = *(const uint4*)(s+24);
  }
  if (tid < 512) { int c = tid>>4; vs[c*168 + 144 + (tid&15)] = 0; } // zero K-pad of v
  for (int j=0;j<4;j++){ int idx = tid + j*576; int row = idx>>4;
    if (row < 144) Ps[row*168 + 144 + (idx&15)] = 0; }               // zero K-pad of P
  __syncthreads();

  size_t winbase = (size_t)(lon*64 + w)*144;
  int r0 = wv*16;
  int l15 = lane & 15, lg = lane >> 4;

  // token A-frags (serve as both A and B operands; identical lane mapping)
  short8 af[6];
  {
    const u16* arow = A + (winbase + r0 + l15)*DIM + 8*lg;
    #pragma unroll
    for (int k0=0;k0<6;k0++) af[k0] = *(const short8*)(arow + k0*32);
  }
  const float qscale = 0.17677669529663687f; // 1/sqrt(32)

  // q,k swapped (A=Ws rows, B=af): D[row=wcol, col=token] -> packed [token][hd] writes
  #pragma unroll
  for (int mt=0; mt<2; mt++) {
    f32x4 acc = {0.f,0.f,0.f,0.f};
    const u16* wrow = Ws + (mt*16 + l15)*200 + 8*lg;
    #pragma unroll
    for (int k0=0;k0<6;k0++) acc = MFMA(*(const short8*)(wrow + k0*32), af[k0], acc);
    short4v pk;
    #pragma unroll
    for (int i=0;i<4;i++) pk[i] = (short)f2bf((acc[i] + qkvb[h*32 + mt*16 + 4*lg + i])*qscale);
    *(short4v*)(qs + (r0 + l15)*40 + mt*16 + 4*lg) = pk;
  }
  #pragma unroll
  for (int mt=0; mt<2; mt++) {
    f32x4 acc = {0.f,0.f,0.f,0.f};
    const u16* wrow = Ws + (32 + mt*16 + l15)*200 + 8*lg;
    #pragma unroll
    for (int k0=0;k0<6;k0++) acc = MFMA(*(const short8*)(wrow + k0*32), af[k0], acc);
    short4v pk;
    #pragma unroll
    for (int i=0;i<4;i++) pk[i] = (short)f2bf(acc[i] + qkvb[192 + h*32 + mt*16 + 4*lg + i]);
    *(short4v*)(ks_ + (r0 + l15)*40 + mt*16 + 4*lg) = pk;
  }
  // v normal (A=af, B=Ws): D[row=token, col=vd] -> packed transposed [vd][token] writes
  #pragma unroll
  for (int ct=0; ct<2; ct++) {
    f32x4 acc = {0.f,0.f,0.f,0.f};
    const u16* wrow = Ws + (64 + ct*16 + l15)*200 + 8*lg;
    #pragma unroll
    for (int k0=0;k0<6;k0++) acc = MFMA(af[k0], *(const short8*)(wrow + k0*32), acc);
    float bias = qkvb[384 + h*32 + ct*16 + l15];
    short4v pk;
    #pragma unroll
    for (int i=0;i<4;i++) pk[i] = (short)f2bf(acc[i] + bias);
    *(short4v*)(vs + (ct*16 + l15)*168 + r0 + 4*lg) = pk;
  }
  __syncthreads();

  // S^T = mfma(A=ks rows m, B=qs own-token cols): sa[mt][i] = S[n=r0+l15][m=mt*16+4lg+i]
  short8 bq = *(const short8*)(qs + (r0 + l15)*40 + 8*lg);
  f32x4 sa[9];
  #pragma unroll
  for (int mt=0; mt<9; mt++) {
    f32x4 z = {0.f,0.f,0.f,0.f};
    sa[mt] = MFMA(*(const short8*)(ks_ + (mt*16 + l15)*40 + 8*lg), bq, z);
  }
  // + bias(+mask): one 8B coalesced load per m-tile
  {
    const u16* bb = Bexp + (((size_t)wh*9 + wv)*9)*256 + lane*4;
    #pragma unroll
    for (int mt=0; mt<9; mt++) {
      short4v pk = *(const short4v*)(bb + mt*256);
      #pragma unroll
      for (int i=0;i<4;i++) sa[mt][i] += bf2f((u16)pk[i]);
    }
  }
  // softmax over m: fully per-lane (36 vals) + 2 shuffles; no max-pass (|S| bounded,
  // masked entries exp(-100) -> 0 exactly as softmax needs)
  float rsum = 0.f;
  #pragma unroll
  for (int mt=0; mt<9; mt++)
    #pragma unroll
    for (int i=0;i<4;i++) { float e = __expf(sa[mt][i]); sa[mt][i] = e; rsum += e; }
  rsum += __shfl_xor(rsum, 16);
  rsum += __shfl_xor(rsum, 32);
  float rinv = 1.f / rsum;
  // P -> LDS [n][m], packed 8B writes, own rows only
  #pragma unroll
  for (int mt=0; mt<9; mt++) {
    short4v pk;
    #pragma unroll
    for (int i=0;i<4;i++) pk[i] = (short)f2bf(sa[mt][i]);
    *(short4v*)(Ps + (r0 + l15)*168 + mt*16 + 4*lg) = pk;
  }

  // O^T = mfma(A=vs rows d, B=Ps own-token cols): packed 8B global stores
  #pragma unroll
  for (int ct2=0; ct2<2; ct2++) {
    f32x4 acc = {0.f,0.f,0.f,0.f};
    const u16* vr = vs + (ct2*16 + l15)*168 + 8*lg;
    const u16* pr = Ps + (r0 + l15)*168 + 8*lg;
    #pragma unroll
    for (int k0=0;k0<5;k0++) acc = MFMA(*(const short8*)(vr + 32*k0), *(const short8*)(pr + 32*k0), acc);
    short4v pk;
    #pragma unroll
    for (int i=0;i<4;i++) pk[i] = (short)f2bf(acc[i]*rinv);
    *(short4v*)(O + (winbase + r0 + l15)*DIM + h*32 + ct2*16 + 4*lg) = pk;
  }
}

// ---------------- K4: proj + window reverse + residual + fused LN2 ----------------
#define SMEMP (73728 + 512)
__global__ __launch_bounds__(512, 4) void proj_ln2_kernel(
    const u16* __restrict__ AT,   // windowed attn bf16 [138240][192]
    const u16* __restrict__ Pw,   // proj_w_t bf16 [192][192]
    const float* __restrict__ pb, const float* __restrict__ x,
    const float* __restrict__ n2g, const float* __restrict__ n2b,
    float* __restrict__ out, u16* __restrict__ Y)
{
  extern __shared__ char smem[];
  u16* Pws = (u16*)smem;                  // swizzled [192][192]
  int* tokmap = (int*)(smem + 73728);
  int tid = threadIdx.x;
  size_t rbase = (size_t)blockIdx.x*128;
  #pragma unroll
  for (int j=0;j<9;j++){                  // 4608 granules of 16B
    int g = j*512 + tid;
    int row = g/24, jj = g - row*24;
    uint4 t = *(const uint4*)(Pw + (size_t)row*192 + jj*8);
    *(uint4*)(Pws + row*192 + ((jj ^ (row&7))*8)) = t;
  }
  if (tid < 128) tokmap[tid] = win_to_tok((int)rbase + tid);
  __syncthreads();

  int lane = tid&63, wv = tid>>6, r0 = wv*16;
  int l15 = lane&15, lg = lane>>4;
  short8 af[6];
  const u16* arow = AT + (rbase + r0 + l15)*DIM + 8*lg;
  #pragma unroll
  for (int k0=0;k0<6;k0++) af[k0] = *(const short8*)(arow + k0*32);

  f32x4 acc[12];
  #pragma unroll
  for (int ct=0; ct<12; ct++) {
    f32x4 a = {0.f,0.f,0.f,0.f};
    const u16* wr = Pws + (ct*16+l15)*192;
    #pragma unroll
    for (int k0=0;k0<6;k0++) a = MFMA(af[k0], *(const short8*)(wr + (((k0*4+lg)^(l15&7))*8)), a);
    acc[ct] = a;
  }
  int toks[4];
  #pragma unroll
  for (int i=0;i<4;i++) toks[i] = tokmap[r0 + 4*lg + i];
  // x2 = x + attn_proj + bias -> out; keep in regs for LN
  #pragma unroll
  for (int ct=0; ct<12; ct++) {
    int col = ct*16+l15;
    float bias = pb[col];
    #pragma unroll
    for (int i=0;i<4;i++){
      size_t o = (size_t)toks[i]*DIM + col;
      float v = x[o] + acc[ct][i] + bias;
      out[o] = v;
      acc[ct][i] = v;
    }
  }
  // fused LN2 over the 192 cols (12 regs x 16 lanes)
  float s[4] = {0,0,0,0};
  #pragma unroll
  for (int ct=0; ct<12; ct++) for (int i=0;i<4;i++) s[i] += acc[ct][i];
  #pragma unroll
  for (int i=0;i<4;i++){ for (int m=1;m<16;m<<=1) s[i] += __shfl_xor(s[i], m, 16); s[i] *= (1.f/192.f); }
  float q[4] = {0,0,0,0};
  #pragma unroll
  for (int ct=0; ct<12; ct++) for (int i=0;i<4;i++){ float d = acc[ct][i]-s[i]; q[i] += d*d; }
  #pragma unroll
  for (int i=0;i<4;i++){ for (int m=1;m<16;m<<=1) q[i] += __shfl_xor(q[i], m, 16); q[i] = rsqrtf(q[i]*(1.f/192.f)+1e-5f); }
  #pragma unroll
  for (int ct=0; ct<12; ct++) {
    int col = ct*16+l15;
    float gg = n2g[col], bb = n2b[col];
    #pragma unroll
    for (int i=0;i<4;i++)
      Y[(size_t)toks[i]*DIM + col] = f2bf((acc[ct][i]-s[i])*q[i]*gg + bb);
  }
}

// ---------------- K5: fused MLP, double-buffered async weight staging ----------------
// LDS: B0 [64][192] 24576 | B1 [192][64] 24576 | Hs [128][72] 18432 = 67584
#define SMEM5 67584
__global__ __launch_bounds__(512, 4) void mlp_kernel(
    const u16* __restrict__ Y,    // ln2 out bf16 [138240][192] (token order)
    const u16* __restrict__ W1f,  // [12][64][24][8]
    const float* __restrict__ b1,
    const u16* __restrict__ W2f,  // [12][192][8][8]
    const float* __restrict__ b2,
    float* __restrict__ out)
{
  extern __shared__ char smem[];
  u16* B0 = (u16*)smem;
  u16* B1 = (u16*)(smem + 24576);
  u16* Hs = (u16*)(smem + 49152);
  int tid = threadIdx.x;
  size_t rbase = (size_t)blockIdx.x*128;
  int lane = tid&63, wv = tid>>6, r0 = wv*16;
  int l15 = lane&15, lg = lane>>4;

  // A-frags direct from global (one-time)
  short8 af[6];
  {
    const u16* yrow = Y + (rbase + r0 + l15)*DIM + 8*lg;
    #pragma unroll
    for (int k0=0;k0<6;k0++) af[k0] = *(const short8*)(yrow + k0*32);
  }

  // prologue: stage W1 chunk 0 -> B0
  #pragma unroll
  for (int j=0;j<3;j++) gl_lds16(W1f + (size_t)tid*8 + j*4096, B0 + tid*8 + j*4096);
  __syncthreads();

  f32x4 acc2[12];
  #pragma unroll
  for (int i=0;i<12;i++) acc2[i] = (f32x4){0.f,0.f,0.f,0.f};

  for (int ch=0; ch<12; ch++) {
    // prefetch W2(ch) -> B1 (B1 free since last fc2's sync)
    {
      const u16* src = W2f + (size_t)ch*12288 + tid*8;
      #pragma unroll
      for (int j=0;j<3;j++) gl_lds16(src + j*4096, B1 + tid*8 + j*4096);
    }
    // fc1: 4 col tiles x 6 k, B from B0
    #pragma unroll
    for (int ct=0; ct<4; ct++) {
      f32x4 a1 = {0.f,0.f,0.f,0.f};
      const u16* wr = B0 + (ct*16+l15)*192;
      #pragma unroll
      for (int k0=0;k0<6;k0++) a1 = MFMA(af[k0], *(const short8*)(wr + (((k0*4+lg)^(l15&7))*8)), a1);
      float bb = b1[ch*64 + ct*16 + l15];
      #pragma unroll
      for (int i=0;i<4;i++){
        float v = a1[i] + bb;
        float u = v*(0.79788456080286536f + 0.03567740813636141f*v*v);
        float e = __expf(2.f*u);
        float th = 1.f - 2.f/(e + 1.f);
        Hs[(r0 + 4*lg + i)*72 + ct*16 + l15] = f2bf(0.5f*v*(1.f + th));
      }
    }
    __syncthreads();   // B1 staged complete; all waves done reading B0

    // prefetch W1(ch+1) -> B0
    if (ch < 11) {
      const u16* src = W1f + (size_t)(ch+1)*12288 + tid*8;
      #pragma unroll
      for (int j=0;j<3;j++) gl_lds16(src + j*4096, B0 + tid*8 + j*4096);
    }
    // fc2: A = Hs (own rows), B from B1; accumulate
    #pragma unroll
    for (int k2=0; k2<2; k2++) {
      short8 ah = *(const short8*)(Hs + (r0+l15)*72 + k2*32 + 8*lg);
      #pragma unroll
      for (int ct2=0; ct2<12; ct2++) {
        const u16* wr2 = B1 + (ct2*16+l15)*64 + (((k2*4+lg)^(l15&7))*8);
        acc2[ct2] = MFMA(ah, *(const short8*)(wr2), acc2[ct2]);
      }
    }
    __syncthreads();   // B0 staged complete; all waves done reading B1
  }
  #pragma unroll
  for (int ct2=0; ct2<12; ct2++) {
    int col = ct2*16+l15;
    float bb = b2[col];
    #pragma unroll
    for (int i=0;i<4;i++){
      size_t o = (rbase + r0 + 4*lg + i)*DIM + col;
      out[o] = out[o] + acc2[ct2][i] + bb;
    }
  }
}

// ---------------- launcher ----------------
extern "C" void kernel_launch(void* const* d_in, const int* in_sizes, int n_in,
                              void* d_out, int out_size, void* d_ws, size_t ws_size,
                              hipStream_t stream) {
  const float* x    = (const float*)d_in[0];
  const float* n1g  = (const float*)d_in[1];
  const float* n1b  = (const float*)d_in[2];
  const float* qkvw = (const float*)d_in[3];
  const float* qkvb = (const float*)d_in[4];
  const float* eb   = (const float*)d_in[5];
  const float* projw= (const float*)d_in[6];
  const float* projb= (const float*)d_in[7];
  const float* n2g  = (const float*)d_in[8];
  const float* n2b  = (const float*)d_in[9];
  const float* fc1w = (const float*)d_in[10];
  const float* fc1b = (const float*)d_in[11];
  const float* fc2w = (const float*)d_in[12];
  const float* fc2b = (const float*)d_in[13];
  float* out = (float*)d_out;
  char* ws = (char*)d_ws;

  u16* A   = (u16*)(ws);                 // 53,084,160 B  (LN1 out; later LN2 out Y)
  u16* AT  = (u16*)(ws + 53084160);      // 53,084,160 B
  u16* Wq  = (u16*)(ws + 106168320);     // qkv_w_t   221,184 B
  u16* Pw  = (u16*)(ws + 106389504);     // proj_w_t   73,728 B
  u16* W1f = (u16*)(ws + 106463232);     // fc1 frag-major 294,912 B
  u16* W2f = (u16*)(ws + 106758144);     // fc2 frag-major 294,912 B
  u16* Bexp = (u16*)d_out;               // 15.9 MB, dead once proj runs

  hipFuncSetAttribute((const void*)attn_kernel,     hipFuncAttributeMaxDynamicSharedMemorySize, SMEM3);
  hipFuncSetAttribute((const void*)proj_ln2_kernel, hipFuncAttributeMaxDynamicSharedMemorySize, SMEMP);
  hipFuncSetAttribute((const void*)mlp_kernel,      hipFuncAttributeMaxDynamicSharedMemorySize, SMEM5);

  transpose_bf16_kernel<<<432, 256, 0, stream>>>(qkvw, Wq, 192, 576);
  transpose_bf16_kernel<<<144, 256, 0, stream>>>(projw, Pw, 192, 192);
  pf_w1_kernel<<<576, 256, 0, stream>>>(fc1w, W1f);
  pf_w2_kernel<<<576, 256, 0, stream>>>(fc2w, W2f);
  bias_expand_kernel<<<384, 256, 0, stream>>>(eb, Bexp);
  ln1_window_kernel<<<34560, 256, 0, stream>>>(x, n1g, n1b, A);
  attn_kernel<<<5760, 576, SMEM3, stream>>>(A, Wq, qkvb, Bexp, AT);
  proj_ln2_kernel<<<1080, 512, SMEMP, stream>>>(AT, Pw, projb, x, n2g, n2b, out, A);
  mlp_kernel<<<1080, 512, SMEM5, stream>>>(A, W1f, fc1b, W2f, fc2b, out);
}

// Round 5
// 491.538 us; speedup vs baseline: 2.7773x; 1.0202x over previous
//
#include <hip/hip_runtime.h>
#include <hip/hip_bf16.h>
#include <math.h>

typedef unsigned short u16;
typedef __attribute__((ext_vector_type(8))) short short8;   // 8 bf16 MFMA A/B frag
typedef __attribute__((ext_vector_type(4))) short short4v;  // 4 bf16 packed
typedef __attribute__((ext_vector_type(4))) float f32x4;    // MFMA C/D frag

#define MFMA(a,b,c) __builtin_amdgcn_mfma_f32_16x16x32_bf16(a,b,c,0,0,0)
#define DIM 192

__device__ __forceinline__ float bf2f(u16 u){ unsigned v=((unsigned)u)<<16; float f; __builtin_memcpy(&f,&v,4); return f; }
__device__ __forceinline__ u16 f2bf(float f){ unsigned v; __builtin_memcpy(&v,&f,4); v = v + 0x7fffu + ((v>>16)&1u); return (u16)(v>>16); }

__device__ __forceinline__ void gl_lds16(const u16* g, u16* l){
  __builtin_amdgcn_global_load_lds((const __attribute__((address_space(1))) unsigned int*)g,
                                   (__attribute__((address_space(3))) unsigned int*)l, 16, 0, 0);
}

// windowed row -> original token index (inverse of roll(-1,-3,-6) + partition)
__device__ __forceinline__ int win_to_tok(int r){
  int lon = r/9216; int rem = r - lon*9216;      // 9216 = 64*144
  int w = rem/144, n = rem - w*144;
  int ip=w>>4, il=w&15;
  int wp=n/72, t=n-wp*72, wl=t/12, ww=t-wl*12;
  int p=ip*2+wp, la=il*6+wl, lo=lon*12+ww;
  int p0=p+1;  if(p0>=8)   p0-=8;
  int la0=la+3; if(la0>=96) la0-=96;
  int lo0=lo+6; if(lo0>=180)lo0-=180;
  return (p0*96+la0)*180+lo0;
}

// ---------------- K1: LN1 + roll + window partition -> bf16 A ----------------
__global__ __launch_bounds__(256) void ln1_window_kernel(
    const float* __restrict__ x, const float* __restrict__ g, const float* __restrict__ b,
    u16* __restrict__ A)
{
  int r = blockIdx.x*4 + (threadIdx.x>>6);
  int lane = threadIdx.x & 63;
  size_t src = (size_t)win_to_tok(r)*DIM;
  float v0=x[src+lane], v1=x[src+64+lane], v2=x[src+128+lane];
  float s=v0+v1+v2;
  for(int m=32;m>=1;m>>=1) s += __shfl_xor(s,m);
  float mean = s*(1.f/192.f);
  float d0=v0-mean,d1=v1-mean,d2=v2-mean;
  float q=d0*d0+d1*d1+d2*d2;
  for(int m=32;m>=1;m>>=1) q += __shfl_xor(q,m);
  float rstd = rsqrtf(q*(1.f/192.f)+1e-5f);
  size_t o = (size_t)r*DIM;
  A[o+lane]     = f2bf(d0*rstd*g[lane]     + b[lane]);
  A[o+64+lane]  = f2bf(d1*rstd*g[64+lane]  + b[64+lane]);
  A[o+128+lane] = f2bf(d2*rstd*g[128+lane] + b[128+lane]);
}

// ---------------- K2: transpose fp32 [K][N] -> bf16 [N][K] (qkv_w, proj_w) ----------------
__global__ __launch_bounds__(256) void transpose_bf16_kernel(
    const float* __restrict__ src, u16* __restrict__ dst, int K, int N)
{
  int idx = blockIdx.x*256 + threadIdx.x;
  if (idx >= K*N) return;
  int k = idx / N, n = idx - k*N;
  dst[n*K + k] = f2bf(src[idx]);
}

// ---------------- K2b: preformat fc1 -> frag-major, XOR-swizzle baked ----------------
// W1f[ch 12][r 64][g 24][e 8]: = fc1w[k=(g^(r&7))*8+e][col=ch*64+r]
__global__ __launch_bounds__(256) void pf_w1_kernel(const float* __restrict__ fc1w, u16* __restrict__ W1f){
  int idx = blockIdx.x*256 + threadIdx.x;      // 147456 total
  int e = idx & 7, g3 = idx >> 3;
  int g = g3 % 24, r3 = g3 / 24;
  int r = r3 & 63, ch = r3 >> 6;
  int k = ((g ^ (r&7))<<3) + e;
  W1f[idx] = f2bf(fc1w[(size_t)k*768 + ch*64 + r]);
}
// W2f[ch 12][r 192][g 8][e 8]: = fc2w[k=ch*64+(g^(r&7))*8+e][col=r]
__global__ __launch_bounds__(256) void pf_w2_kernel(const float* __restrict__ fc2w, u16* __restrict__ W2f){
  int idx = blockIdx.x*256 + threadIdx.x;      // 147456 total
  int e = idx & 7, g3 = idx >> 3;
  int g = g3 & 7, r3 = g3 >> 3;
  int r = r3 % 192, ch = r3 / 192;
  int k = ch*64 + ((g ^ (r&7))<<3) + e;
  W2f[idx] = f2bf(fc2w[(size_t)k*192 + r]);
}

// ---------------- K2c: expand earth bias+mask -> lane-packed Bexp ----------------
// Bexp[wh 384][nt 9][mt 9][lane 64][i 4] bf16:
//   value = bias[n = nt*16 + (lane&15)][m = mt*16 + ((lane>>4)<<2) + i]
__global__ __launch_bounds__(256) void bias_expand_kernel(
    const float* __restrict__ eb, u16* __restrict__ B2)
{
  __shared__ int t1s[144], t2s[144], rgs[144];
  __shared__ float ebs[3312];
  int bid = blockIdx.x;           // bid = w*6 + h
  int w = bid / 6;
  int tid = threadIdx.x;
  if (tid < 144) {
    int n = tid;
    int wp=n/72, t=n-wp*72, wl=t/12, ww=t-wl*12;
    t1s[n] = wp*828 + wl*23 + ww;
    t2s[n] = 1656*wp + 138*wl - ww + 11;
    int ip = w>>4, il = w&15;
    int p = ip*2+wp, la = il*6+wl;
    int rp = (p<6)?0:((p<7)?1:2);
    int rl = (la<90)?0:((la<93)?1:2);
    rgs[n] = rp*3+rl;
  }
  for (int i = tid; i < 3312; i += 256) ebs[i] = eb[(size_t)i*384 + bid];
  __syncthreads();
  size_t ob = (size_t)bid*20736;
  for (int idx = tid; idx < 20736; idx += 256) {
    int i = idx & 3, lane = (idx>>2)&63, t = idx>>8;   // t = nt*9+mt
    int mt = t%9, nt = t/9;
    int n = nt*16 + (lane&15);
    int m = mt*16 + ((lane>>4)<<2) + i;
    float bv = ebs[t1s[n]+t2s[m]];
    bv += (rgs[n]==rgs[m]) ? 0.f : -100.f;
    B2[ob + idx] = f2bf(bv);
  }
}

// ---------------- K3: fused QKV + earth attention per (lon,w,head) ----------------
// S^T / O^T operand-swapped MFMA structure: per-lane register softmax, packed LDS IO.
#define SM_WS   0                  // [96][200] u16  = 38400 B
#define SM_QS   38400              // [144][40] u16  = 11520 B
#define SM_KS   49920              // [144][40] u16  = 11520 B
#define SM_VS   61440              // [32][168] u16  = 10752 B (v transposed, k-padded)
#define SM_PS   72192              // [144][168] u16 = 48384 B ([n][m], m-padded)
#define SMEM3   120576

__global__ __launch_bounds__(576) void attn_kernel(
    const u16* __restrict__ A,      // windowed bf16 [138240][192]
    const u16* __restrict__ Wt,     // qkv_w_t bf16 [576][192]
    const float* __restrict__ qkvb, // [576]
    const u16* __restrict__ Bexp,   // lane-packed [384][9][9][64][4] bf16
    u16* __restrict__ O)            // windowed attn out bf16 [138240][192]
{
  extern __shared__ char smem[];
  u16* Ws = (u16*)(smem + SM_WS);
  u16* qs = (u16*)(smem + SM_QS);
  u16* ks_= (u16*)(smem + SM_KS);
  u16* vs = (u16*)(smem + SM_VS);
  u16* Ps = (u16*)(smem + SM_PS);

  // XCD-aware remap: same (w,h) for all 15 lon -> same XCD, consecutive; h inner within w.
  int bid = blockIdx.x;
  int logical = (bid & 7)*720 + (bid >> 3);     // 5760 = 8*720, bijective
  int lon = logical % 15;
  int wh  = logical / 15;                        // = w*6 + h
  int h = wh % 6, w = wh / 6;
  int tid = threadIdx.x, lane = tid & 63, wv = tid >> 6;

  { // stage per-head weight slice (rows: q|k|v x 32 outcols, [outcol][k])
    int rr = tid % 96, chunk = tid / 96;
    int mat = rr >> 5, c = rr & 31;
    const u16* s = Wt + (size_t)(mat*192 + h*32 + c)*192 + chunk*32;
    u16* d = Ws + rr*200 + chunk*32;
    *(uint4*)(d)    = *(const uint4*)(s);
    *(uint4*)(d+8)  = *(const uint4*)(s+8);
    *(uint4*)(d+16) = *(const uint4*)(s+16);
    *(uint4*)(d+24) = *(const uint4*)(s+24);
  }
  if (tid < 512) { int c = tid>>4; vs[c*168 + 144 + (tid&15)] = 0; } // zero K-pad of v
  for (int j=0;j<4;j++){ int idx = tid + j*576; int row = idx>>4;
    if (row < 144) Ps[row*168 + 144 + (idx&15)] = 0; }               // zero K-pad of P
  __syncthreads();

  size_t winbase = (size_t)(lon*64 + w)*144;
  int r0 = wv*16;
  int l15 = lane & 15, lg = lane >> 4;

  // token A-frags (serve as both A and B operands; identical lane mapping)
  short8 af[6];
  {
    const u16* arow = A + (winbase + r0 + l15)*DIM + 8*lg;
    #pragma unroll
    for (int k0=0;k0<6;k0++) af[k0] = *(const short8*)(arow + k0*32);
  }
  const float qscale = 0.17677669529663687f; // 1/sqrt(32)

  // q,k swapped (A=Ws rows, B=af): D[row=wcol, col=token] -> packed [token][hd] writes
  #pragma unroll
  for (int mt=0; mt<2; mt++) {
    f32x4 acc = {0.f,0.f,0.f,0.f};
    const u16* wrow = Ws + (mt*16 + l15)*200 + 8*lg;
    #pragma unroll
    for (int k0=0;k0<6;k0++) acc = MFMA(*(const short8*)(wrow + k0*32), af[k0], acc);
    short4v pk;
    #pragma unroll
    for (int i=0;i<4;i++) pk[i] = (short)f2bf((acc[i] + qkvb[h*32 + mt*16 + 4*lg + i])*qscale);
    *(short4v*)(qs + (r0 + l15)*40 + mt*16 + 4*lg) = pk;
  }
  #pragma unroll
  for (int mt=0; mt<2; mt++) {
    f32x4 acc = {0.f,0.f,0.f,0.f};
    const u16* wrow = Ws + (32 + mt*16 + l15)*200 + 8*lg;
    #pragma unroll
    for (int k0=0;k0<6;k0++) acc = MFMA(*(const short8*)(wrow + k0*32), af[k0], acc);
    short4v pk;
    #pragma unroll
    for (int i=0;i<4;i++) pk[i] = (short)f2bf(acc[i] + qkvb[192 + h*32 + mt*16 + 4*lg + i]);
    *(short4v*)(ks_ + (r0 + l15)*40 + mt*16 + 4*lg) = pk;
  }
  // v normal (A=af, B=Ws): D[row=token, col=vd] -> packed transposed [vd][token] writes
  #pragma unroll
  for (int ct=0; ct<2; ct++) {
    f32x4 acc = {0.f,0.f,0.f,0.f};
    const u16* wrow = Ws + (64 + ct*16 + l15)*200 + 8*lg;
    #pragma unroll
    for (int k0=0;k0<6;k0++) acc = MFMA(af[k0], *(const short8*)(wrow + k0*32), acc);
    float bias = qkvb[384 + h*32 + ct*16 + l15];
    short4v pk;
    #pragma unroll
    for (int i=0;i<4;i++) pk[i] = (short)f2bf(acc[i] + bias);
    *(short4v*)(vs + (ct*16 + l15)*168 + r0 + 4*lg) = pk;
  }
  __syncthreads();

  // S^T = mfma(A=ks rows m, B=qs own-token cols): sa[mt][i] = S[n=r0+l15][m=mt*16+4lg+i]
  short8 bq = *(const short8*)(qs + (r0 + l15)*40 + 8*lg);
  f32x4 sa[9];
  #pragma unroll
  for (int mt=0; mt<9; mt++) {
    f32x4 z = {0.f,0.f,0.f,0.f};
    sa[mt] = MFMA(*(const short8*)(ks_ + (mt*16 + l15)*40 + 8*lg), bq, z);
  }
  // + bias(+mask): one 8B coalesced load per m-tile
  {
    const u16* bb = Bexp + (((size_t)wh*9 + wv)*9)*256 + lane*4;
    #pragma unroll
    for (int mt=0; mt<9; mt++) {
      short4v pk = *(const short4v*)(bb + mt*256);
      #pragma unroll
      for (int i=0;i<4;i++) sa[mt][i] += bf2f((u16)pk[i]);
    }
  }
  // softmax over m: fully per-lane (36 vals) + 2 shuffles; no max-pass (|S| bounded,
  // masked entries exp(-100) -> 0 exactly as softmax needs)
  float rsum = 0.f;
  #pragma unroll
  for (int mt=0; mt<9; mt++)
    #pragma unroll
    for (int i=0;i<4;i++) { float e = __expf(sa[mt][i]); sa[mt][i] = e; rsum += e; }
  rsum += __shfl_xor(rsum, 16);
  rsum += __shfl_xor(rsum, 32);
  float rinv = 1.f / rsum;
  // P -> LDS [n][m], packed 8B writes, own rows only
  #pragma unroll
  for (int mt=0; mt<9; mt++) {
    short4v pk;
    #pragma unroll
    for (int i=0;i<4;i++) pk[i] = (short)f2bf(sa[mt][i]);
    *(short4v*)(Ps + (r0 + l15)*168 + mt*16 + 4*lg) = pk;
  }

  // O^T = mfma(A=vs rows d, B=Ps own-token cols): packed 8B global stores
  #pragma unroll
  for (int ct2=0; ct2<2; ct2++) {
    f32x4 acc = {0.f,0.f,0.f,0.f};
    const u16* vr = vs + (ct2*16 + l15)*168 + 8*lg;
    const u16* pr = Ps + (r0 + l15)*168 + 8*lg;
    #pragma unroll
    for (int k0=0;k0<5;k0++) acc = MFMA(*(const short8*)(vr + 32*k0), *(const short8*)(pr + 32*k0), acc);
    short4v pk;
    #pragma unroll
    for (int i=0;i<4;i++) pk[i] = (short)f2bf(acc[i]*rinv);
    *(short4v*)(O + (winbase + r0 + l15)*DIM + h*32 + ct2*16 + 4*lg) = pk;
  }
}

// ---------------- K4: proj + window reverse + residual + fused LN2 ----------------
#define SMEMP (73728 + 512)
__global__ __launch_bounds__(512, 4) void proj_ln2_kernel(
    const u16* __restrict__ AT,   // windowed attn bf16 [138240][192]
    const u16* __restrict__ Pw,   // proj_w_t bf16 [192][192]
    const float* __restrict__ pb, const float* __restrict__ x,
    const float* __restrict__ n2g, const float* __restrict__ n2b,
    float* __restrict__ out, u16* __restrict__ Y)
{
  extern __shared__ char smem[];
  u16* Pws = (u16*)smem;                  // swizzled [192][192]
  int* tokmap = (int*)(smem + 73728);
  int tid = threadIdx.x;
  size_t rbase = (size_t)blockIdx.x*128;
  #pragma unroll
  for (int j=0;j<9;j++){                  // 4608 granules of 16B
    int g = j*512 + tid;
    int row = g/24, jj = g - row*24;
    uint4 t = *(const uint4*)(Pw + (size_t)row*192 + jj*8);
    *(uint4*)(Pws + row*192 + ((jj ^ (row&7))*8)) = t;
  }
  if (tid < 128) tokmap[tid] = win_to_tok((int)rbase + tid);
  __syncthreads();

  int lane = tid&63, wv = tid>>6, r0 = wv*16;
  int l15 = lane&15, lg = lane>>4;
  short8 af[6];
  const u16* arow = AT + (rbase + r0 + l15)*DIM + 8*lg;
  #pragma unroll
  for (int k0=0;k0<6;k0++) af[k0] = *(const short8*)(arow + k0*32);

  f32x4 acc[12];
  #pragma unroll
  for (int ct=0; ct<12; ct++) {
    f32x4 a = {0.f,0.f,0.f,0.f};
    const u16* wr = Pws + (ct*16+l15)*192;
    #pragma unroll
    for (int k0=0;k0<6;k0++) a = MFMA(af[k0], *(const short8*)(wr + (((k0*4+lg)^(l15&7))*8)), a);
    acc[ct] = a;
  }
  int toks[4];
  #pragma unroll
  for (int i=0;i<4;i++) toks[i] = tokmap[r0 + 4*lg + i];
  // x2 = x + attn_proj + bias -> out; keep in regs for LN
  #pragma unroll
  for (int ct=0; ct<12; ct++) {
    int col = ct*16+l15;
    float bias = pb[col];
    #pragma unroll
    for (int i=0;i<4;i++){
      size_t o = (size_t)toks[i]*DIM + col;
      float v = x[o] + acc[ct][i] + bias;
      out[o] = v;
      acc[ct][i] = v;
    }
  }
  // fused LN2 over the 192 cols (12 regs x 16 lanes)
  float s[4] = {0,0,0,0};
  #pragma unroll
  for (int ct=0; ct<12; ct++) for (int i=0;i<4;i++) s[i] += acc[ct][i];
  #pragma unroll
  for (int i=0;i<4;i++){ for (int m=1;m<16;m<<=1) s[i] += __shfl_xor(s[i], m, 16); s[i] *= (1.f/192.f); }
  float q[4] = {0,0,0,0};
  #pragma unroll
  for (int ct=0; ct<12; ct++) for (int i=0;i<4;i++){ float d = acc[ct][i]-s[i]; q[i] += d*d; }
  #pragma unroll
  for (int i=0;i<4;i++){ for (int m=1;m<16;m<<=1) q[i] += __shfl_xor(q[i], m, 16); q[i] = rsqrtf(q[i]*(1.f/192.f)+1e-5f); }
  #pragma unroll
  for (int ct=0; ct<12; ct++) {
    int col = ct*16+l15;
    float gg = n2g[col], bb = n2b[col];
    #pragma unroll
    for (int i=0;i<4;i++)
      Y[(size_t)toks[i]*DIM + col] = f2bf((acc[ct][i]-s[i])*q[i]*gg + bb);
  }
}

// ---------------- K5: fused MLP v3 -- 1024 thr, 256 rows/block, dbuf weights ----------------
// LDS: B0 [64][192] 24576 | B1 [192][64] 24576 | Hs [256][72] 36864 = 86016
#define SMEM5 86016
__global__ __launch_bounds__(1024, 4) void mlp_kernel(
    const u16* __restrict__ Y,    // ln2 out bf16 [138240][192] (token order)
    const u16* __restrict__ W1f,  // [12][64][24][8]
    const float* __restrict__ b1,
    const u16* __restrict__ W2f,  // [12][192][8][8]
    const float* __restrict__ b2,
    float* __restrict__ out)
{
  extern __shared__ char smem[];
  u16* B0 = (u16*)smem;
  u16* B1 = (u16*)(smem + 24576);
  u16* Hs = (u16*)(smem + 49152);
  int tid = threadIdx.x;
  size_t rbase = (size_t)blockIdx.x*256;
  int lane = tid&63, wv = tid>>6, r0 = wv*16;
  int l15 = lane&15, lg = lane>>4;

  // A-frags direct from global (one-time)
  short8 af[6];
  {
    const u16* yrow = Y + (rbase + r0 + l15)*DIM + 8*lg;
    #pragma unroll
    for (int k0=0;k0<6;k0++) af[k0] = *(const short8*)(yrow + k0*32);
  }

  // prologue: stage W1 chunk 0 -> B0 (24576 B = 1536 granules; 1024 + 512)
  gl_lds16(W1f + (size_t)tid*8, B0 + tid*8);
  if (tid < 512) gl_lds16(W1f + (size_t)(1024+tid)*8, B0 + (1024+tid)*8);
  __syncthreads();

  f32x4 acc2[12];
  #pragma unroll
  for (int i=0;i<12;i++) acc2[i] = (f32x4){0.f,0.f,0.f,0.f};

  const float GA = -1.5957691216057307f;   // -2*0.7978845608
  const float GB = -0.07135481627272283f;  // -2*0.0356774081

  for (int ch=0; ch<12; ch++) {
    // prefetch W2(ch) -> B1 (B1 free since last fc2's sync)
    {
      const u16* s2 = W2f + (size_t)ch*12288;
      gl_lds16(s2 + (size_t)tid*8, B1 + tid*8);
      if (tid < 512) gl_lds16(s2 + (size_t)(1024+tid)*8, B1 + (1024+tid)*8);
    }
    // fc1: 4 col tiles x 6 k, B from B0; tanh-GELU in sigmoid form
    #pragma unroll
    for (int ct=0; ct<4; ct++) {
      f32x4 a1 = {0.f,0.f,0.f,0.f};
      const u16* wr = B0 + (ct*16+l15)*192;
      #pragma unroll
      for (int k0=0;k0<6;k0++) a1 = MFMA(af[k0], *(const short8*)(wr + (((k0*4+lg)^(l15&7))*8)), a1);
      float bb = b1[ch*64 + ct*16 + l15];
      #pragma unroll
      for (int i=0;i<4;i++){
        float v = a1[i] + bb;
        float t = v*v;
        float m = fmaf(t, GB, GA);           // -2u/v
        float e = __expf(v*m);               // exp(-2u)
        float hgl = v*__builtin_amdgcn_rcpf(1.f + e);  // v*sigmoid(2u)
        Hs[(r0 + 4*lg + i)*72 + ct*16 + l15] = f2bf(hgl);
      }
    }
    __syncthreads();   // B1 staged complete; all waves done reading B0

    // prefetch W1(ch+1) -> B0
    if (ch < 11) {
      const u16* s1 = W1f + (size_t)(ch+1)*12288;
      gl_lds16(s1 + (size_t)tid*8, B0 + tid*8);
      if (tid < 512) gl_lds16(s1 + (size_t)(1024+tid)*8, B0 + (1024+tid)*8);
    }
    // fc2: A = Hs (own rows), B from B1; accumulate
    #pragma unroll
    for (int k2=0; k2<2; k2++) {
      short8 ah = *(const short8*)(Hs + (r0+l15)*72 + k2*32 + 8*lg);
      #pragma unroll
      for (int ct2=0; ct2<12; ct2++) {
        const u16* wr2 = B1 + (ct2*16+l15)*64 + (((k2*4+lg)^(l15&7))*8);
        acc2[ct2] = MFMA(ah, *(const short8*)(wr2), acc2[ct2]);
      }
    }
    __syncthreads();   // B0 staged complete; all waves done reading B1
  }
  #pragma unroll
  for (int ct2=0; ct2<12; ct2++) {
    int col = ct2*16+l15;
    float bb = b2[col];
    #pragma unroll
    for (int i=0;i<4;i++){
      size_t o = (rbase + r0 + 4*lg + i)*DIM + col;
      out[o] = out[o] + acc2[ct2][i] + bb;
    }
  }
}

// ---------------- launcher ----------------
extern "C" void kernel_launch(void* const* d_in, const int* in_sizes, int n_in,
                              void* d_out, int out_size, void* d_ws, size_t ws_size,
                              hipStream_t stream) {
  const float* x    = (const float*)d_in[0];
  const float* n1g  = (const float*)d_in[1];
  const float* n1b  = (const float*)d_in[2];
  const float* qkvw = (const float*)d_in[3];
  const float* qkvb = (const float*)d_in[4];
  const float* eb   = (const float*)d_in[5];
  const float* projw= (const float*)d_in[6];
  const float* projb= (const float*)d_in[7];
  const float* n2g  = (const float*)d_in[8];
  const float* n2b  = (const float*)d_in[9];
  const float* fc1w = (const float*)d_in[10];
  const float* fc1b = (const float*)d_in[11];
  const float* fc2w = (const float*)d_in[12];
  const float* fc2b = (const float*)d_in[13];
  float* out = (float*)d_out;
  char* ws = (char*)d_ws;

  u16* A   = (u16*)(ws);                 // 53,084,160 B  (LN1 out; later LN2 out Y)
  u16* AT  = (u16*)(ws + 53084160);      // 53,084,160 B
  u16* Wq  = (u16*)(ws + 106168320);     // qkv_w_t   221,184 B
  u16* Pw  = (u16*)(ws + 106389504);     // proj_w_t   73,728 B
  u16* W1f = (u16*)(ws + 106463232);     // fc1 frag-major 294,912 B
  u16* W2f = (u16*)(ws + 106758144);     // fc2 frag-major 294,912 B
  u16* Bexp = (u16*)d_out;               // 15.9 MB, dead once proj runs

  hipFuncSetAttribute((const void*)attn_kernel,     hipFuncAttributeMaxDynamicSharedMemorySize, SMEM3);
  hipFuncSetAttribute((const void*)proj_ln2_kernel, hipFuncAttributeMaxDynamicSharedMemorySize, SMEMP);
  hipFuncSetAttribute((const void*)mlp_kernel,      hipFuncAttributeMaxDynamicSharedMemorySize, SMEM5);

  transpose_bf16_kernel<<<432, 256, 0, stream>>>(qkvw, Wq, 192, 576);
  transpose_bf16_kernel<<<144, 256, 0, stream>>>(projw, Pw, 192, 192);
  pf_w1_kernel<<<576, 256, 0, stream>>>(fc1w, W1f);
  pf_w2_kernel<<<576, 256, 0, stream>>>(fc2w, W2f);
  bias_expand_kernel<<<384, 256, 0, stream>>>(eb, Bexp);
  ln1_window_kernel<<<34560, 256, 0, stream>>>(x, n1g, n1b, A);
  attn_kernel<<<5760, 576, SMEM3, stream>>>(A, Wq, qkvb, Bexp, AT);
  proj_ln2_kernel<<<1080, 512, SMEMP, stream>>>(AT, Pw, projb, x, n2g, n2b, out, A);
  mlp_kernel<<<540, 1024, SMEM5, stream>>>(A, W1f, fc1b, W2f, fc2b, out);
}

// Round 7
// 468.974 us; speedup vs baseline: 2.9109x; 1.0481x over previous
//
#include <hip/hip_runtime.h>
#include <hip/hip_bf16.h>
#include <math.h>

typedef unsigned short u16;
typedef __attribute__((ext_vector_type(8))) short short8;   // 8 bf16 MFMA A/B frag
typedef __attribute__((ext_vector_type(4))) short short4v;  // 4 bf16 packed
typedef __attribute__((ext_vector_type(4))) float f32x4;    // MFMA C/D frag

#define MFMA(a,b,c) __builtin_amdgcn_mfma_f32_16x16x32_bf16(a,b,c,0,0,0)
#define DIM 192

__device__ __forceinline__ float bf2f(u16 u){ unsigned v=((unsigned)u)<<16; float f; __builtin_memcpy(&f,&v,4); return f; }
__device__ __forceinline__ u16 f2bf(float f){ unsigned v; __builtin_memcpy(&v,&f,4); v = v + 0x7fffu + ((v>>16)&1u); return (u16)(v>>16); }

__device__ __forceinline__ void gl_lds16(const u16* g, u16* l){
  __builtin_amdgcn_global_load_lds((const __attribute__((address_space(1))) unsigned int*)g,
                                   (__attribute__((address_space(3))) unsigned int*)l, 16, 0, 0);
}

// windowed row -> original token index (inverse of roll(-1,-3,-6) + partition)
__device__ __forceinline__ int win_to_tok(int r){
  int lon = r/9216; int rem = r - lon*9216;      // 9216 = 64*144
  int w = rem/144, n = rem - w*144;
  int ip=w>>4, il=w&15;
  int wp=n/72, t=n-wp*72, wl=t/12, ww=t-wl*12;
  int p=ip*2+wp, la=il*6+wl, lo=lon*12+ww;
  int p0=p+1;  if(p0>=8)   p0-=8;
  int la0=la+3; if(la0>=96) la0-=96;
  int lo0=lo+6; if(lo0>=180)lo0-=180;
  return (p0*96+la0)*180+lo0;
}

// ---------------- K1: LN1 + roll + window partition -> bf16 A ----------------
__global__ __launch_bounds__(256) void ln1_window_kernel(
    const float* __restrict__ x, const float* __restrict__ g, const float* __restrict__ b,
    u16* __restrict__ A)
{
  int r = blockIdx.x*4 + (threadIdx.x>>6);
  int lane = threadIdx.x & 63;
  size_t src = (size_t)win_to_tok(r)*DIM;
  float v0=x[src+lane], v1=x[src+64+lane], v2=x[src+128+lane];
  float s=v0+v1+v2;
  for(int m=32;m>=1;m>>=1) s += __shfl_xor(s,m);
  float mean = s*(1.f/192.f);
  float d0=v0-mean,d1=v1-mean,d2=v2-mean;
  float q=d0*d0+d1*d1+d2*d2;
  for(int m=32;m>=1;m>>=1) q += __shfl_xor(q,m);
  float rstd = rsqrtf(q*(1.f/192.f)+1e-5f);
  size_t o = (size_t)r*DIM;
  A[o+lane]     = f2bf(d0*rstd*g[lane]     + b[lane]);
  A[o+64+lane]  = f2bf(d1*rstd*g[64+lane]  + b[64+lane]);
  A[o+128+lane] = f2bf(d2*rstd*g[128+lane] + b[128+lane]);
}

// ---------------- K2: transpose fp32 [K][N] -> bf16 [N][K] (qkv_w, proj_w) ----------------
__global__ __launch_bounds__(256) void transpose_bf16_kernel(
    const float* __restrict__ src, u16* __restrict__ dst, int K, int N)
{
  int idx = blockIdx.x*256 + threadIdx.x;
  if (idx >= K*N) return;
  int k = idx / N, n = idx - k*N;
  dst[n*K + k] = f2bf(src[idx]);
}

// ---------------- K2b: preformat fc1 -> frag-major, XOR-swizzle baked ----------------
// W1f[hc 24][r 32][g 24][e 8]: = fc1w[k=(g^(r&7))*8+e][col=hc*32+r]  (hc-contiguous halves)
__global__ __launch_bounds__(256) void pf_w1_kernel(const float* __restrict__ fc1w, u16* __restrict__ W1f){
  int idx = blockIdx.x*256 + threadIdx.x;      // 147456 total
  int e = idx & 7, g3 = idx >> 3;
  int g = g3 % 24, r3 = g3 / 24;
  int r = r3 & 31, hc = r3 >> 5;
  int k = ((g ^ (r&7))<<3) + e;
  W1f[idx] = f2bf(fc1w[(size_t)k*768 + hc*32 + r]);
}
// W2f[hc 24][r 192][g 4][e 8]: = fc2w[k=hc*32+(g^(r&3))*8+e][col=r]
__global__ __launch_bounds__(256) void pf_w2_kernel(const float* __restrict__ fc2w, u16* __restrict__ W2f){
  int idx = blockIdx.x*256 + threadIdx.x;      // 147456 total
  int e = idx & 7, g3 = idx >> 3;
  int g = g3 & 3, r3 = g3 >> 2;
  int r = r3 % 192, hc = r3 / 192;
  int k = hc*32 + ((g ^ (r&3))<<3) + e;
  W2f[idx] = f2bf(fc2w[(size_t)k*192 + r]);
}

// ---------------- K2c: expand earth bias+mask -> lane-packed Bexp ----------------
__global__ __launch_bounds__(256) void bias_expand_kernel(
    const float* __restrict__ eb, u16* __restrict__ B2)
{
  __shared__ int t1s[144], t2s[144], rgs[144];
  __shared__ float ebs[3312];
  int bid = blockIdx.x;           // bid = w*6 + h
  int w = bid / 6;
  int tid = threadIdx.x;
  if (tid < 144) {
    int n = tid;
    int wp=n/72, t=n-wp*72, wl=t/12, ww=t-wl*12;
    t1s[n] = wp*828 + wl*23 + ww;
    t2s[n] = 1656*wp + 138*wl - ww + 11;
    int ip = w>>4, il = w&15;
    int p = ip*2+wp, la = il*6+wl;
    int rp = (p<6)?0:((p<7)?1:2);
    int rl = (la<90)?0:((la<93)?1:2);
    rgs[n] = rp*3+rl;
  }
  for (int i = tid; i < 3312; i += 256) ebs[i] = eb[(size_t)i*384 + bid];
  __syncthreads();
  size_t ob = (size_t)bid*20736;
  for (int idx = tid; idx < 20736; idx += 256) {
    int i = idx & 3, lane = (idx>>2)&63, t = idx>>8;   // t = nt*9+mt
    int mt = t%9, nt = t/9;
    int n = nt*16 + (lane&15);
    int m = mt*16 + ((lane>>4)<<2) + i;
    float bv = ebs[t1s[n]+t2s[m]];
    bv += (rgs[n]==rgs[m]) ? 0.f : -100.f;
    B2[ob + idx] = f2bf(bv);
  }
}

// ---------------- K3: fused QKV + earth attention per (lon,w,head) ----------------
#define SM_WS   0                  // [96][200] u16  = 38400 B
#define SM_QS   38400              // [144][40] u16  = 11520 B
#define SM_KS   49920              // [144][40] u16  = 11520 B
#define SM_VS   61440              // [32][168] u16  = 10752 B (v transposed, k-padded)
#define SM_PS   72192              // [144][168] u16 = 48384 B ([n][m], m-padded)
#define SMEM3   120576

__global__ __launch_bounds__(576) void attn_kernel(
    const u16* __restrict__ A,      // windowed bf16 [138240][192]
    const u16* __restrict__ Wt,     // qkv_w_t bf16 [576][192]
    const float* __restrict__ qkvb, // [576]
    const u16* __restrict__ Bexp,   // lane-packed [384][9][9][64][4] bf16
    u16* __restrict__ O)            // windowed attn out bf16 [138240][192]
{
  extern __shared__ char smem[];
  u16* Ws = (u16*)(smem + SM_WS);
  u16* qs = (u16*)(smem + SM_QS);
  u16* ks_= (u16*)(smem + SM_KS);
  u16* vs = (u16*)(smem + SM_VS);
  u16* Ps = (u16*)(smem + SM_PS);

  // XCD-aware remap: same (w,h) for all 15 lon -> same XCD, consecutive; h inner within w.
  int bid = blockIdx.x;
  int logical = (bid & 7)*720 + (bid >> 3);     // 5760 = 8*720, bijective
  int lon = logical % 15;
  int wh  = logical / 15;                        // = w*6 + h
  int h = wh % 6, w = wh / 6;
  int tid = threadIdx.x, lane = tid & 63, wv = tid >> 6;

  { // stage per-head weight slice (rows: q|k|v x 32 outcols, [outcol][k])
    int rr = tid % 96, chunk = tid / 96;
    int mat = rr >> 5, c = rr & 31;
    const u16* s = Wt + (size_t)(mat*192 + h*32 + c)*192 + chunk*32;
    u16* d = Ws + rr*200 + chunk*32;
    *(uint4*)(d)    = *(const uint4*)(s);
    *(uint4*)(d+8)  = *(const uint4*)(s+8);
    *(uint4*)(d+16) = *(const uint4*)(s+16);
    *(uint4*)(d+24) = *(const uint4*)(s+24);
  }
  if (tid < 512) { int c = tid>>4; vs[c*168 + 144 + (tid&15)] = 0; } // zero K-pad of v
  for (int j=0;j<4;j++){ int idx = tid + j*576; int row = idx>>4;
    if (row < 144) Ps[row*168 + 144 + (idx&15)] = 0; }               // zero K-pad of P
  __syncthreads();

  size_t winbase = (size_t)(lon*64 + w)*144;
  int r0 = wv*16;
  int l15 = lane & 15, lg = lane >> 4;

  // token A-frags (serve as both A and B operands; identical lane mapping)
  short8 af[6];
  {
    const u16* arow = A + (winbase + r0 + l15)*DIM + 8*lg;
    #pragma unroll
    for (int k0=0;k0<6;k0++) af[k0] = *(const short8*)(arow + k0*32);
  }
  const float qscale = 0.17677669529663687f; // 1/sqrt(32)

  // q,k swapped (A=Ws rows, B=af): D[row=wcol, col=token] -> packed [token][hd] writes
  #pragma unroll
  for (int mt=0; mt<2; mt++) {
    f32x4 acc = {0.f,0.f,0.f,0.f};
    const u16* wrow = Ws + (mt*16 + l15)*200 + 8*lg;
    #pragma unroll
    for (int k0=0;k0<6;k0++) acc = MFMA(*(const short8*)(wrow + k0*32), af[k0], acc);
    short4v pk;
    #pragma unroll
    for (int i=0;i<4;i++) pk[i] = (short)f2bf((acc[i] + qkvb[h*32 + mt*16 + 4*lg + i])*qscale);
    *(short4v*)(qs + (r0 + l15)*40 + mt*16 + 4*lg) = pk;
  }
  #pragma unroll
  for (int mt=0; mt<2; mt++) {
    f32x4 acc = {0.f,0.f,0.f,0.f};
    const u16* wrow = Ws + (32 + mt*16 + l15)*200 + 8*lg;
    #pragma unroll
    for (int k0=0;k0<6;k0++) acc = MFMA(*(const short8*)(wrow + k0*32), af[k0], acc);
    short4v pk;
    #pragma unroll
    for (int i=0;i<4;i++) pk[i] = (short)f2bf(acc[i] + qkvb[192 + h*32 + mt*16 + 4*lg + i]);
    *(short4v*)(ks_ + (r0 + l15)*40 + mt*16 + 4*lg) = pk;
  }
  // v normal (A=af, B=Ws): D[row=token, col=vd] -> packed transposed [vd][token] writes
  #pragma unroll
  for (int ct=0; ct<2; ct++) {
    f32x4 acc = {0.f,0.f,0.f,0.f};
    const u16* wrow = Ws + (64 + ct*16 + l15)*200 + 8*lg;
    #pragma unroll
    for (int k0=0;k0<6;k0++) acc = MFMA(af[k0], *(const short8*)(wrow + k0*32), acc);
    float bias = qkvb[384 + h*32 + ct*16 + l15];
    short4v pk;
    #pragma unroll
    for (int i=0;i<4;i++) pk[i] = (short)f2bf(acc[i] + bias);
    *(short4v*)(vs + (ct*16 + l15)*168 + r0 + 4*lg) = pk;
  }
  __syncthreads();

  // S^T = mfma(A=ks rows m, B=qs own-token cols): sa[mt][i] = S[n=r0+l15][m=mt*16+4lg+i]
  short8 bq = *(const short8*)(qs + (r0 + l15)*40 + 8*lg);
  f32x4 sa[9];
  #pragma unroll
  for (int mt=0; mt<9; mt++) {
    f32x4 z = {0.f,0.f,0.f,0.f};
    sa[mt] = MFMA(*(const short8*)(ks_ + (mt*16 + l15)*40 + 8*lg), bq, z);
  }
  // + bias(+mask): one 8B coalesced load per m-tile
  {
    const u16* bb = Bexp + (((size_t)wh*9 + wv)*9)*256 + lane*4;
    #pragma unroll
    for (int mt=0; mt<9; mt++) {
      short4v pk = *(const short4v*)(bb + mt*256);
      #pragma unroll
      for (int i=0;i<4;i++) sa[mt][i] += bf2f((u16)pk[i]);
    }
  }
  // softmax over m: fully per-lane (36 vals) + 2 shuffles; no max-pass
  float rsum = 0.f;
  #pragma unroll
  for (int mt=0; mt<9; mt++)
    #pragma unroll
    for (int i=0;i<4;i++) { float e = __expf(sa[mt][i]); sa[mt][i] = e; rsum += e; }
  rsum += __shfl_xor(rsum, 16);
  rsum += __shfl_xor(rsum, 32);
  float rinv = 1.f / rsum;
  // P -> LDS [n][m], packed 8B writes, own rows only
  #pragma unroll
  for (int mt=0; mt<9; mt++) {
    short4v pk;
    #pragma unroll
    for (int i=0;i<4;i++) pk[i] = (short)f2bf(sa[mt][i]);
    *(short4v*)(Ps + (r0 + l15)*168 + mt*16 + 4*lg) = pk;
  }

  // O^T = mfma(A=vs rows d, B=Ps own-token cols): packed 8B global stores
  #pragma unroll
  for (int ct2=0; ct2<2; ct2++) {
    f32x4 acc = {0.f,0.f,0.f,0.f};
    const u16* vr = vs + (ct2*16 + l15)*168 + 8*lg;
    const u16* pr = Ps + (r0 + l15)*168 + 8*lg;
    #pragma unroll
    for (int k0=0;k0<5;k0++) acc = MFMA(*(const short8*)(vr + 32*k0), *(const short8*)(pr + 32*k0), acc);
    short4v pk;
    #pragma unroll
    for (int i=0;i<4;i++) pk[i] = (short)f2bf(acc[i]*rinv);
    *(short4v*)(O + (winbase + r0 + l15)*DIM + h*32 + ct2*16 + 4*lg) = pk;
  }
}

// ---------------- K4: proj + window reverse + residual + fused LN2 ----------------
#define SMEMP (73728 + 512)
__global__ __launch_bounds__(512, 4) void proj_ln2_kernel(
    const u16* __restrict__ AT,   // windowed attn bf16 [138240][192]
    const u16* __restrict__ Pw,   // proj_w_t bf16 [192][192]
    const float* __restrict__ pb, const float* __restrict__ x,
    const float* __restrict__ n2g, const float* __restrict__ n2b,
    float* __restrict__ out, u16* __restrict__ Y)
{
  extern __shared__ char smem[];
  u16* Pws = (u16*)smem;                  // swizzled [192][192]
  int* tokmap = (int*)(smem + 73728);
  int tid = threadIdx.x;
  size_t rbase = (size_t)blockIdx.x*128;
  #pragma unroll
  for (int j=0;j<9;j++){                  // 4608 granules of 16B
    int g = j*512 + tid;
    int row = g/24, jj = g - row*24;
    uint4 t = *(const uint4*)(Pw + (size_t)row*192 + jj*8);
    *(uint4*)(Pws + row*192 + ((jj ^ (row&7))*8)) = t;
  }
  if (tid < 128) tokmap[tid] = win_to_tok((int)rbase + tid);
  __syncthreads();

  int lane = tid&63, wv = tid>>6, r0 = wv*16;
  int l15 = lane&15, lg = lane>>4;
  short8 af[6];
  const u16* arow = AT + (rbase + r0 + l15)*DIM + 8*lg;
  #pragma unroll
  for (int k0=0;k0<6;k0++) af[k0] = *(const short8*)(arow + k0*32);

  f32x4 acc[12];
  #pragma unroll
  for (int ct=0; ct<12; ct++) {
    f32x4 a = {0.f,0.f,0.f,0.f};
    const u16* wr = Pws + (ct*16+l15)*192;
    #pragma unroll
    for (int k0=0;k0<6;k0++) a = MFMA(af[k0], *(const short8*)(wr + (((k0*4+lg)^(l15&7))*8)), a);
    acc[ct] = a;
  }
  int toks[4];
  #pragma unroll
  for (int i=0;i<4;i++) toks[i] = tokmap[r0 + 4*lg + i];
  // x2 = x + attn_proj + bias -> out; keep in regs for LN
  #pragma unroll
  for (int ct=0; ct<12; ct++) {
    int col = ct*16+l15;
    float bias = pb[col];
    #pragma unroll
    for (int i=0;i<4;i++){
      size_t o = (size_t)toks[i]*DIM + col;
      float v = x[o] + acc[ct][i] + bias;
      out[o] = v;
      acc[ct][i] = v;
    }
  }
  // fused LN2 over the 192 cols (12 regs x 16 lanes)
  float s[4] = {0,0,0,0};
  #pragma unroll
  for (int ct=0; ct<12; ct++) for (int i=0;i<4;i++) s[i] += acc[ct][i];
  #pragma unroll
  for (int i=0;i<4;i++){ for (int m=1;m<16;m<<=1) s[i] += __shfl_xor(s[i], m, 16); s[i] *= (1.f/192.f); }
  float q[4] = {0,0,0,0};
  #pragma unroll
  for (int ct=0; ct<12; ct++) for (int i=0;i<4;i++){ float d = acc[ct][i]-s[i]; q[i] += d*d; }
  #pragma unroll
  for (int i=0;i<4;i++){ for (int m=1;m<16;m<<=1) q[i] += __shfl_xor(q[i], m, 16); q[i] = rsqrtf(q[i]*(1.f/192.f)+1e-5f); }
  #pragma unroll
  for (int ct=0; ct<12; ct++) {
    int col = ct*16+l15;
    float gg = n2g[col], bb = n2b[col];
    #pragma unroll
    for (int i=0;i<4;i++)
      Y[(size_t)toks[i]*DIM + col] = f2bf((acc[ct][i]-s[i])*q[i]*gg + bb);
  }
}

// ---------------- K5: fused MLP v4b -- 24 half-chunks, 4-buffer ring, 2-deep prefetch ----
// LDS: W1b0 12288 | W1b1 12288 | W2b0 12288 | W2b1 12288 | Hs [128][40] 10240 = 59392
#define SMEM5 59392
__global__ __launch_bounds__(512, 4) void mlp_kernel(
    const u16* __restrict__ Y,    // ln2 out bf16 [138240][192] (token order)
    const u16* __restrict__ W1f,  // [24][32][24][8]
    const float* __restrict__ b1,
    const u16* __restrict__ W2f,  // [24][192][4][8]
    const float* __restrict__ b2,
    float* __restrict__ out)
{
  extern __shared__ char smem[];
  u16* W1b0 = (u16*)smem;
  u16* W1b1 = (u16*)(smem + 12288);
  u16* W2b0 = (u16*)(smem + 24576);
  u16* W2b1 = (u16*)(smem + 36864);
  u16* Hs   = (u16*)(smem + 49152);
  int tid = threadIdx.x;
  size_t rbase = (size_t)blockIdx.x*128;
  int lane = tid&63, wv = tid>>6, r0 = wv*16;
  int l15 = lane&15, lg = lane>>4;

  // A-frags direct from global (one-time)
  short8 af[6];
  {
    const u16* yrow = Y + (rbase + r0 + l15)*DIM + 8*lg;
    #pragma unroll
    for (int k0=0;k0<6;k0++) af[k0] = *(const short8*)(yrow + k0*32);
  }

  // prologue: stage hc0 -> (W1b0,W2b0), hc1 -> (W1b1,W2b1). 12288B = 768 granules/buf.
  {
    gl_lds16(W1f + (size_t)tid*8, W1b0 + tid*8);
    if (tid < 256) gl_lds16(W1f + (size_t)(512+tid)*8, W1b0 + (512+tid)*8);
    gl_lds16(W2f + (size_t)tid*8, W2b0 + tid*8);
    if (tid < 256) gl_lds16(W2f + (size_t)(512+tid)*8, W2b0 + (512+tid)*8);
    const u16* s1 = W1f + 6144; const u16* s2 = W2f + 6144;
    gl_lds16(s1 + (size_t)tid*8, W1b1 + tid*8);
    if (tid < 256) gl_lds16(s1 + (size_t)(512+tid)*8, W1b1 + (512+tid)*8);
    gl_lds16(s2 + (size_t)tid*8, W2b1 + tid*8);
    if (tid < 256) gl_lds16(s2 + (size_t)(512+tid)*8, W2b1 + (512+tid)*8);
  }
  __syncthreads();

  f32x4 acc2[12];
  #pragma unroll
  for (int i=0;i<12;i++) acc2[i] = (f32x4){0.f,0.f,0.f,0.f};

  const float GA = -1.5957691216057307f;   // -2*0.7978845608
  const float GB = -0.07135481627272283f;  // -2*0.0356774081

  for (int hc=0; hc<24; hc++) {
    u16* B1w = (hc&1) ? W1b1 : W1b0;
    u16* B2w = (hc&1) ? W2b1 : W2b0;
    // fc1: 2 col tiles x 6 k, B from B1w; tanh-GELU sigmoid form -> Hs (wave-private rows)
    #pragma unroll
    for (int ct=0; ct<2; ct++) {
      f32x4 a1 = {0.f,0.f,0.f,0.f};
      const u16* wr = B1w + (ct*16+l15)*192;
      #pragma unroll
      for (int k0=0;k0<6;k0++) a1 = MFMA(af[k0], *(const short8*)(wr + (((k0*4+lg)^(l15&7))*8)), a1);
      float bb = b1[hc*32 + ct*16 + l15];
      #pragma unroll
      for (int i=0;i<4;i++){
        float v = a1[i] + bb;
        float t = v*v;
        float m = fmaf(t, GB, GA);
        float e = __expf(v*m);
        float hgl = v*__builtin_amdgcn_rcpf(1.f + e);
        Hs[(r0 + 4*lg + i)*40 + ct*16 + l15] = f2bf(hgl);
      }
    }
    // fc2: A = Hs own rows (32 k), B from B2w (row stride 32 u16); accumulate
    {
      short8 ah = *(const short8*)(Hs + (r0+l15)*40 + 8*lg);
      #pragma unroll
      for (int ct2=0; ct2<12; ct2++) {
        const u16* wr2 = B2w + (ct2*16+l15)*32 + ((lg ^ (l15&3))*8);
        acc2[ct2] = MFMA(ah, *(const short8*)(wr2), acc2[ct2]);
      }
    }
    __syncthreads();   // frees this iteration's buffers; drains loads issued last iter
    // prefetch hc+2 into the buffers just freed
    if (hc < 22) {
      const u16* s1 = W1f + (size_t)(hc+2)*6144;
      const u16* s2 = W2f + (size_t)(hc+2)*6144;
      u16* d1 = (hc&1) ? W1b1 : W1b0;
      u16* d2 = (hc&1) ? W2b1 : W2b0;
      gl_lds16(s1 + (size_t)tid*8, d1 + tid*8);
      if (tid < 256) gl_lds16(s1 + (size_t)(512+tid)*8, d1 + (512+tid)*8);
      gl_lds16(s2 + (size_t)tid*8, d2 + tid*8);
      if (tid < 256) gl_lds16(s2 + (size_t)(512+tid)*8, d2 + (512+tid)*8);
    }
  }
  #pragma unroll
  for (int ct2=0; ct2<12; ct2++) {
    int col = ct2*16+l15;
    float bb = b2[col];
    #pragma unroll
    for (int i=0;i<4;i++){
      size_t o = (rbase + r0 + 4*lg + i)*DIM + col;
      out[o] = out[o] + acc2[ct2][i] + bb;
    }
  }
}

// ---------------- launcher ----------------
extern "C" void kernel_launch(void* const* d_in, const int* in_sizes, int n_in,
                              void* d_out, int out_size, void* d_ws, size_t ws_size,
                              hipStream_t stream) {
  const float* x    = (const float*)d_in[0];
  const float* n1g  = (const float*)d_in[1];
  const float* n1b  = (const float*)d_in[2];
  const float* qkvw = (const float*)d_in[3];
  const float* qkvb = (const float*)d_in[4];
  const float* eb   = (const float*)d_in[5];
  const float* projw= (const float*)d_in[6];
  const float* projb= (const float*)d_in[7];
  const float* n2g  = (const float*)d_in[8];
  const float* n2b  = (const float*)d_in[9];
  const float* fc1w = (const float*)d_in[10];
  const float* fc1b = (const float*)d_in[11];
  const float* fc2w = (const float*)d_in[12];
  const float* fc2b = (const float*)d_in[13];
  float* out = (float*)d_out;
  char* ws = (char*)d_ws;

  u16* A   = (u16*)(ws);                 // 53,084,160 B  (LN1 out; later LN2 out Y)
  u16* AT  = (u16*)(ws + 53084160);      // 53,084,160 B
  u16* Wq  = (u16*)(ws + 106168320);     // qkv_w_t   221,184 B
  u16* Pw  = (u16*)(ws + 106389504);     // proj_w_t   73,728 B
  u16* W1f = (u16*)(ws + 106463232);     // fc1 frag-major 294,912 B
  u16* W2f = (u16*)(ws + 106758144);     // fc2 frag-major 294,912 B
  u16* Bexp = (u16*)d_out;               // 15.9 MB, dead once proj runs

  hipFuncSetAttribute((const void*)attn_kernel,     hipFuncAttributeMaxDynamicSharedMemorySize, SMEM3);
  hipFuncSetAttribute((const void*)proj_ln2_kernel, hipFuncAttributeMaxDynamicSharedMemorySize, SMEMP);
  hipFuncSetAttribute((const void*)mlp_kernel,      hipFuncAttributeMaxDynamicSharedMemorySize, SMEM5);

  transpose_bf16_kernel<<<432, 256, 0, stream>>>(qkvw, Wq, 192, 576);
  transpose_bf16_kernel<<<144, 256, 0, stream>>>(projw, Pw, 192, 192);
  pf_w1_kernel<<<576, 256, 0, stream>>>(fc1w, W1f);
  pf_w2_kernel<<<576, 256, 0, stream>>>(fc2w, W2f);
  bias_expand_kernel<<<384, 256, 0, stream>>>(eb, Bexp);
  ln1_window_kernel<<<34560, 256, 0, stream>>>(x, n1g, n1b, A);
  attn_kernel<<<5760, 576, SMEM3, stream>>>(A, Wq, qkvb, Bexp, AT);
  proj_ln2_kernel<<<1080, 512, SMEMP, stream>>>(AT, Pw, projb, x, n2g, n2b, out, A);
  mlp_kernel<<<1080, 512, SMEM5, stream>>>(A, W1f, fc1b, W2f, fc2b, out);
}

// Round 8
// 442.325 us; speedup vs baseline: 3.0863x; 1.0602x over previous
//
#include <hip/hip_runtime.h>
#include <hip/hip_bf16.h>
#include <math.h>

typedef unsigned short u16;
typedef __attribute__((ext_vector_type(8))) short short8;   // 8 bf16 MFMA A/B frag
typedef __attribute__((ext_vector_type(4))) short short4v;  // 4 bf16 packed
typedef __attribute__((ext_vector_type(4))) float f32x4;    // MFMA C/D frag

#define MFMA(a,b,c) __builtin_amdgcn_mfma_f32_16x16x32_bf16(a,b,c,0,0,0)
#define DIM 192

__device__ __forceinline__ float bf2f(u16 u){ unsigned v=((unsigned)u)<<16; float f; __builtin_memcpy(&f,&v,4); return f; }
__device__ __forceinline__ u16 f2bf(float f){ unsigned v; __builtin_memcpy(&v,&f,4); v = v + 0x7fffu + ((v>>16)&1u); return (u16)(v>>16); }

__device__ __forceinline__ void gl_lds16(const u16* g, u16* l){
  __builtin_amdgcn_global_load_lds((const __attribute__((address_space(1))) unsigned int*)g,
                                   (__attribute__((address_space(3))) unsigned int*)l, 16, 0, 0);
}

// windowed row -> original token index (inverse of roll(-1,-3,-6) + partition)
__device__ __forceinline__ int win_to_tok(int r){
  int lon = r/9216; int rem = r - lon*9216;      // 9216 = 64*144
  int w = rem/144, n = rem - w*144;
  int ip=w>>4, il=w&15;
  int wp=n/72, t=n-wp*72, wl=t/12, ww=t-wl*12;
  int p=ip*2+wp, la=il*6+wl, lo=lon*12+ww;
  int p0=p+1;  if(p0>=8)   p0-=8;
  int la0=la+3; if(la0>=96) la0-=96;
  int lo0=lo+6; if(lo0>=180)lo0-=180;
  return (p0*96+la0)*180+lo0;
}

// ---------------- K1: LN1 + roll + window partition -> bf16 A ----------------
__global__ __launch_bounds__(256) void ln1_window_kernel(
    const float* __restrict__ x, const float* __restrict__ g, const float* __restrict__ b,
    u16* __restrict__ A)
{
  int r = blockIdx.x*4 + (threadIdx.x>>6);
  int lane = threadIdx.x & 63;
  size_t src = (size_t)win_to_tok(r)*DIM;
  float v0=x[src+lane], v1=x[src+64+lane], v2=x[src+128+lane];
  float s=v0+v1+v2;
  for(int m=32;m>=1;m>>=1) s += __shfl_xor(s,m);
  float mean = s*(1.f/192.f);
  float d0=v0-mean,d1=v1-mean,d2=v2-mean;
  float q=d0*d0+d1*d1+d2*d2;
  for(int m=32;m>=1;m>>=1) q += __shfl_xor(q,m);
  float rstd = rsqrtf(q*(1.f/192.f)+1e-5f);
  size_t o = (size_t)r*DIM;
  A[o+lane]     = f2bf(d0*rstd*g[lane]     + b[lane]);
  A[o+64+lane]  = f2bf(d1*rstd*g[64+lane]  + b[64+lane]);
  A[o+128+lane] = f2bf(d2*rstd*g[128+lane] + b[128+lane]);
}

// ---------------- K2: transpose fp32 [K][N] -> bf16 [N][K] (qkv_w, proj_w) ----------------
__global__ __launch_bounds__(256) void transpose_bf16_kernel(
    const float* __restrict__ src, u16* __restrict__ dst, int K, int N)
{
  int idx = blockIdx.x*256 + threadIdx.x;
  if (idx >= K*N) return;
  int k = idx / N, n = idx - k*N;
  dst[n*K + k] = f2bf(src[idx]);
}

// ---------------- K2b: preformat fc1 -> frag-major, XOR-swizzle baked ----------------
// W1f[hc 24][r 32][g 24][e 8]: = fc1w[k=(g^(r&7))*8+e][col=hc*32+r]  (hc-contiguous halves)
__global__ __launch_bounds__(256) void pf_w1_kernel(const float* __restrict__ fc1w, u16* __restrict__ W1f){
  int idx = blockIdx.x*256 + threadIdx.x;      // 147456 total
  int e = idx & 7, g3 = idx >> 3;
  int g = g3 % 24, r3 = g3 / 24;
  int r = r3 & 31, hc = r3 >> 5;
  int k = ((g ^ (r&7))<<3) + e;
  W1f[idx] = f2bf(fc1w[(size_t)k*768 + hc*32 + r]);
}
// W2f[hc 24][r 192][g 4][e 8]: = fc2w[k=hc*32+(g^(r&3))*8+e][col=r]
__global__ __launch_bounds__(256) void pf_w2_kernel(const float* __restrict__ fc2w, u16* __restrict__ W2f){
  int idx = blockIdx.x*256 + threadIdx.x;      // 147456 total
  int e = idx & 7, g3 = idx >> 3;
  int g = g3 & 3, r3 = g3 >> 2;
  int r = r3 % 192, hc = r3 / 192;
  int k = hc*32 + ((g ^ (r&3))<<3) + e;
  W2f[idx] = f2bf(fc2w[(size_t)k*192 + r]);
}

// ---------------- K2c: expand earth bias+mask -> lane-packed Bexp ----------------
__global__ __launch_bounds__(256) void bias_expand_kernel(
    const float* __restrict__ eb, u16* __restrict__ B2)
{
  __shared__ int t1s[144], t2s[144], rgs[144];
  __shared__ float ebs[3312];
  int bid = blockIdx.x;           // bid = w*6 + h
  int w = bid / 6;
  int tid = threadIdx.x;
  if (tid < 144) {
    int n = tid;
    int wp=n/72, t=n-wp*72, wl=t/12, ww=t-wl*12;
    t1s[n] = wp*828 + wl*23 + ww;
    t2s[n] = 1656*wp + 138*wl - ww + 11;
    int ip = w>>4, il = w&15;
    int p = ip*2+wp, la = il*6+wl;
    int rp = (p<6)?0:((p<7)?1:2);
    int rl = (la<90)?0:((la<93)?1:2);
    rgs[n] = rp*3+rl;
  }
  for (int i = tid; i < 3312; i += 256) ebs[i] = eb[(size_t)i*384 + bid];
  __syncthreads();
  size_t ob = (size_t)bid*20736;
  for (int idx = tid; idx < 20736; idx += 256) {
    int i = idx & 3, lane = (idx>>2)&63, t = idx>>8;   // t = nt*9+mt
    int mt = t%9, nt = t/9;
    int n = nt*16 + (lane&15);
    int m = mt*16 + ((lane>>4)<<2) + i;
    float bv = ebs[t1s[n]+t2s[m]];
    bv += (rgs[n]==rgs[m]) ? 0.f : -100.f;
    B2[ob + idx] = f2bf(bv);
  }
}

// ---------------- K3: fused QKV + earth attention per (lon,w,head) ----------------
// LDS time-multiplex: Ws [96][192] swizzled (dead after QKV); qs/ks [144][40]
// (dead after S^T); Ps [144][168] OVERLAYS Ws+qs. vs [32][168] persistent.
#define SM_WS   0                  // 36864 B  (96*192*2)
#define SM_QS   36864              // 11520 B  (144*40*2)
#define SM_KS   48384              // 11520 B
#define SM_VS   59904              // 10752 B  (32*168*2)
#define SM_PS   0                  // 48384 B  overlays Ws+qs (time-multiplexed)
#define SMEM3   70656              // 2 blocks/CU (160 KB LDS)

__global__ __launch_bounds__(576) void attn_kernel(
    const u16* __restrict__ A,      // windowed bf16 [138240][192]
    const u16* __restrict__ Wt,     // qkv_w_t bf16 [576][192]
    const float* __restrict__ qkvb, // [576]
    const u16* __restrict__ Bexp,   // lane-packed [384][9][9][64][4] bf16
    u16* __restrict__ O)            // windowed attn out bf16 [138240][192]
{
  extern __shared__ char smem[];
  u16* Ws = (u16*)(smem + SM_WS);
  u16* qs = (u16*)(smem + SM_QS);
  u16* ks_= (u16*)(smem + SM_KS);
  u16* vs = (u16*)(smem + SM_VS);
  u16* Ps = (u16*)(smem + SM_PS);

  // XCD-aware remap: same (w,h) for all 15 lon -> same XCD, consecutive.
  int bid = blockIdx.x;
  int logical = (bid & 7)*720 + (bid >> 3);     // 5760 = 8*720, bijective
  int lon = logical % 15;
  int wh  = logical / 15;                        // = w*6 + h
  int h = wh % 6, w = wh / 6;
  int tid = threadIdx.x, lane = tid & 63, wv = tid >> 6;

  { // stage per-head weight slice into swizzled Ws (granule g^(row&7))
    int rr = tid % 96, chunk = tid / 96;         // chunk 0..5 -> granules 4c..4c+3
    int mat = rr >> 5, c = rr & 31;
    const u16* s = Wt + (size_t)(mat*192 + h*32 + c)*192 + chunk*32;
    uint4 t0 = *(const uint4*)(s);
    uint4 t1 = *(const uint4*)(s+8);
    uint4 t2 = *(const uint4*)(s+16);
    uint4 t3 = *(const uint4*)(s+24);
    u16* d = Ws + rr*192;
    int r7 = rr & 7, g0 = chunk*4;
    *(uint4*)(d + ((g0  )^r7)*8) = t0;
    *(uint4*)(d + ((g0+1)^r7)*8) = t1;
    *(uint4*)(d + ((g0+2)^r7)*8) = t2;
    *(uint4*)(d + ((g0+3)^r7)*8) = t3;
  }
  if (tid < 512) { int c = tid>>4; vs[c*168 + 144 + (tid&15)] = 0; } // zero K-pad of v
  __syncthreads();

  size_t winbase = (size_t)(lon*64 + w)*144;
  int r0 = wv*16;
  int l15 = lane & 15, lg = lane >> 4;
  int sw7 = l15 & 7;

  // token A-frags (serve as both A and B operands; identical lane mapping)
  short8 af[6];
  {
    const u16* arow = A + (winbase + r0 + l15)*DIM + 8*lg;
    #pragma unroll
    for (int k0=0;k0<6;k0++) af[k0] = *(const short8*)(arow + k0*32);
  }
  const float qscale = 0.17677669529663687f; // 1/sqrt(32)

  // q,k swapped (A=Ws rows, B=af): D[row=wcol, col=token] -> packed [token][hd] writes
  #pragma unroll
  for (int mt=0; mt<2; mt++) {
    f32x4 acc = {0.f,0.f,0.f,0.f};
    const u16* wrow = Ws + (mt*16 + l15)*192;
    #pragma unroll
    for (int k0=0;k0<6;k0++) acc = MFMA(*(const short8*)(wrow + ((k0*4+lg)^sw7)*8), af[k0], acc);
    short4v pk;
    #pragma unroll
    for (int i=0;i<4;i++) pk[i] = (short)f2bf((acc[i] + qkvb[h*32 + mt*16 + 4*lg + i])*qscale);
    *(short4v*)(qs + (r0 + l15)*40 + mt*16 + 4*lg) = pk;
  }
  #pragma unroll
  for (int mt=0; mt<2; mt++) {
    f32x4 acc = {0.f,0.f,0.f,0.f};
    const u16* wrow = Ws + (32 + mt*16 + l15)*192;
    #pragma unroll
    for (int k0=0;k0<6;k0++) acc = MFMA(*(const short8*)(wrow + ((k0*4+lg)^sw7)*8), af[k0], acc);
    short4v pk;
    #pragma unroll
    for (int i=0;i<4;i++) pk[i] = (short)f2bf(acc[i] + qkvb[192 + h*32 + mt*16 + 4*lg + i]);
    *(short4v*)(ks_ + (r0 + l15)*40 + mt*16 + 4*lg) = pk;
  }
  // v normal (A=af, B=Ws): D[row=token, col=vd] -> packed transposed [vd][token] writes
  #pragma unroll
  for (int ct=0; ct<2; ct++) {
    f32x4 acc = {0.f,0.f,0.f,0.f};
    const u16* wrow = Ws + (64 + ct*16 + l15)*192;
    #pragma unroll
    for (int k0=0;k0<6;k0++) acc = MFMA(af[k0], *(const short8*)(wrow + ((k0*4+lg)^sw7)*8), acc);
    float bias = qkvb[384 + h*32 + ct*16 + l15];
    short4v pk;
    #pragma unroll
    for (int i=0;i<4;i++) pk[i] = (short)f2bf(acc[i] + bias);
    *(short4v*)(vs + (ct*16 + l15)*168 + r0 + 4*lg) = pk;
  }
  __syncthreads();   // qkv staged; Ws now dead

  // S^T = mfma(A=ks rows m, B=qs own-token cols): sa[mt][i] = S[n=r0+l15][m=mt*16+4lg+i]
  short8 bq = *(const short8*)(qs + (r0 + l15)*40 + 8*lg);
  f32x4 sa[9];
  #pragma unroll
  for (int mt=0; mt<9; mt++) {
    f32x4 z = {0.f,0.f,0.f,0.f};
    sa[mt] = MFMA(*(const short8*)(ks_ + (mt*16 + l15)*40 + 8*lg), bq, z);
  }
  __syncthreads();   // all S^T reads done; qs/ks dead -> Ps may overwrite

  // + bias(+mask): one 8B coalesced load per m-tile
  {
    const u16* bb = Bexp + (((size_t)wh*9 + wv)*9)*256 + lane*4;
    #pragma unroll
    for (int mt=0; mt<9; mt++) {
      short4v pk = *(const short4v*)(bb + mt*256);
      #pragma unroll
      for (int i=0;i<4;i++) sa[mt][i] += bf2f((u16)pk[i]);
    }
  }
  // softmax over m: fully per-lane (36 vals) + 2 shuffles; no max-pass
  float rsum = 0.f;
  #pragma unroll
  for (int mt=0; mt<9; mt++)
    #pragma unroll
    for (int i=0;i<4;i++) { float e = __expf(sa[mt][i]); sa[mt][i] = e; rsum += e; }
  rsum += __shfl_xor(rsum, 16);
  rsum += __shfl_xor(rsum, 32);
  float rinv = 1.f / rsum;
  // P -> LDS [n][m] (overlay region), packed 8B writes, wave-private rows
  #pragma unroll
  for (int mt=0; mt<9; mt++) {
    short4v pk;
    #pragma unroll
    for (int i=0;i<4;i++) pk[i] = (short)f2bf(sa[mt][i]);
    *(short4v*)(Ps + (r0 + l15)*168 + mt*16 + 4*lg) = pk;
  }
  { // zero this wave's K-pad cols [144,160)
    short4v z = {0,0,0,0};
    *(short4v*)(Ps + (r0 + l15)*168 + 144 + 4*lg) = z;
  }

  // O^T = mfma(A=vs rows d, B=Ps own-token cols): packed 8B global stores
  #pragma unroll
  for (int ct2=0; ct2<2; ct2++) {
    f32x4 acc = {0.f,0.f,0.f,0.f};
    const u16* vr = vs + (ct2*16 + l15)*168 + 8*lg;
    const u16* pr = Ps + (r0 + l15)*168 + 8*lg;
    #pragma unroll
    for (int k0=0;k0<5;k0++) acc = MFMA(*(const short8*)(vr + 32*k0), *(const short8*)(pr + 32*k0), acc);
    short4v pk;
    #pragma unroll
    for (int i=0;i<4;i++) pk[i] = (short)f2bf(acc[i]*rinv);
    *(short4v*)(O + (winbase + r0 + l15)*DIM + h*32 + ct2*16 + 4*lg) = pk;
  }
}

// ---------------- K4: proj + window reverse + residual + fused LN2 ----------------
#define SMEMP (73728 + 512)
__global__ __launch_bounds__(512, 4) void proj_ln2_kernel(
    const u16* __restrict__ AT,   // windowed attn bf16 [138240][192]
    const u16* __restrict__ Pw,   // proj_w_t bf16 [192][192]
    const float* __restrict__ pb, const float* __restrict__ x,
    const float* __restrict__ n2g, const float* __restrict__ n2b,
    float* __restrict__ out, u16* __restrict__ Y)
{
  extern __shared__ char smem[];
  u16* Pws = (u16*)smem;                  // swizzled [192][192]
  int* tokmap = (int*)(smem + 73728);
  int tid = threadIdx.x;
  size_t rbase = (size_t)blockIdx.x*128;
  #pragma unroll
  for (int j=0;j<9;j++){                  // 4608 granules of 16B
    int g = j*512 + tid;
    int row = g/24, jj = g - row*24;
    uint4 t = *(const uint4*)(Pw + (size_t)row*192 + jj*8);
    *(uint4*)(Pws + row*192 + ((jj ^ (row&7))*8)) = t;
  }
  if (tid < 128) tokmap[tid] = win_to_tok((int)rbase + tid);
  __syncthreads();

  int lane = tid&63, wv = tid>>6, r0 = wv*16;
  int l15 = lane&15, lg = lane>>4;
  short8 af[6];
  const u16* arow = AT + (rbase + r0 + l15)*DIM + 8*lg;
  #pragma unroll
  for (int k0=0;k0<6;k0++) af[k0] = *(const short8*)(arow + k0*32);

  f32x4 acc[12];
  #pragma unroll
  for (int ct=0; ct<12; ct++) {
    f32x4 a = {0.f,0.f,0.f,0.f};
    const u16* wr = Pws + (ct*16+l15)*192;
    #pragma unroll
    for (int k0=0;k0<6;k0++) a = MFMA(af[k0], *(const short8*)(wr + (((k0*4+lg)^(l15&7))*8)), a);
    acc[ct] = a;
  }
  int toks[4];
  #pragma unroll
  for (int i=0;i<4;i++) toks[i] = tokmap[r0 + 4*lg + i];
  // x2 = x + attn_proj + bias -> out; keep in regs for LN
  #pragma unroll
  for (int ct=0; ct<12; ct++) {
    int col = ct*16+l15;
    float bias = pb[col];
    #pragma unroll
    for (int i=0;i<4;i++){
      size_t o = (size_t)toks[i]*DIM + col;
      float v = x[o] + acc[ct][i] + bias;
      out[o] = v;
      acc[ct][i] = v;
    }
  }
  // fused LN2 over the 192 cols (12 regs x 16 lanes)
  float s[4] = {0,0,0,0};
  #pragma unroll
  for (int ct=0; ct<12; ct++) for (int i=0;i<4;i++) s[i] += acc[ct][i];
  #pragma unroll
  for (int i=0;i<4;i++){ for (int m=1;m<16;m<<=1) s[i] += __shfl_xor(s[i], m, 16); s[i] *= (1.f/192.f); }
  float q[4] = {0,0,0,0};
  #pragma unroll
  for (int ct=0; ct<12; ct++) for (int i=0;i<4;i++){ float d = acc[ct][i]-s[i]; q[i] += d*d; }
  #pragma unroll
  for (int i=0;i<4;i++){ for (int m=1;m<16;m<<=1) q[i] += __shfl_xor(q[i], m, 16); q[i] = rsqrtf(q[i]*(1.f/192.f)+1e-5f); }
  #pragma unroll
  for (int ct=0; ct<12; ct++) {
    int col = ct*16+l15;
    float gg = n2g[col], bb = n2b[col];
    #pragma unroll
    for (int i=0;i<4;i++)
      Y[(size_t)toks[i]*DIM + col] = f2bf((acc[ct][i]-s[i])*q[i]*gg + bb);
  }
}

// ---------------- K5: fused MLP v4b -- 24 half-chunks, 4-buffer ring, 2-deep prefetch ----
// LDS: W1b0 12288 | W1b1 12288 | W2b0 12288 | W2b1 12288 | Hs [128][40] 10240 = 59392
#define SMEM5 59392
__global__ __launch_bounds__(512, 4) void mlp_kernel(
    const u16* __restrict__ Y,    // ln2 out bf16 [138240][192] (token order)
    const u16* __restrict__ W1f,  // [24][32][24][8]
    const float* __restrict__ b1,
    const u16* __restrict__ W2f,  // [24][192][4][8]
    const float* __restrict__ b2,
    float* __restrict__ out)
{
  extern __shared__ char smem[];
  u16* W1b0 = (u16*)smem;
  u16* W1b1 = (u16*)(smem + 12288);
  u16* W2b0 = (u16*)(smem + 24576);
  u16* W2b1 = (u16*)(smem + 36864);
  u16* Hs   = (u16*)(smem + 49152);
  int tid = threadIdx.x;
  size_t rbase = (size_t)blockIdx.x*128;
  int lane = tid&63, wv = tid>>6, r0 = wv*16;
  int l15 = lane&15, lg = lane>>4;

  // A-frags direct from global (one-time)
  short8 af[6];
  {
    const u16* yrow = Y + (rbase + r0 + l15)*DIM + 8*lg;
    #pragma unroll
    for (int k0=0;k0<6;k0++) af[k0] = *(const short8*)(yrow + k0*32);
  }

  // prologue: stage hc0 -> (W1b0,W2b0), hc1 -> (W1b1,W2b1). 12288B = 768 granules/buf.
  {
    gl_lds16(W1f + (size_t)tid*8, W1b0 + tid*8);
    if (tid < 256) gl_lds16(W1f + (size_t)(512+tid)*8, W1b0 + (512+tid)*8);
    gl_lds16(W2f + (size_t)tid*8, W2b0 + tid*8);
    if (tid < 256) gl_lds16(W2f + (size_t)(512+tid)*8, W2b0 + (512+tid)*8);
    const u16* s1 = W1f + 6144; const u16* s2 = W2f + 6144;
    gl_lds16(s1 + (size_t)tid*8, W1b1 + tid*8);
    if (tid < 256) gl_lds16(s1 + (size_t)(512+tid)*8, W1b1 + (512+tid)*8);
    gl_lds16(s2 + (size_t)tid*8, W2b1 + tid*8);
    if (tid < 256) gl_lds16(s2 + (size_t)(512+tid)*8, W2b1 + (512+tid)*8);
  }
  __syncthreads();

  f32x4 acc2[12];
  #pragma unroll
  for (int i=0;i<12;i++) acc2[i] = (f32x4){0.f,0.f,0.f,0.f};

  const float GA = -1.5957691216057307f;   // -2*0.7978845608
  const float GB = -0.07135481627272283f;  // -2*0.0356774081

  for (int hc=0; hc<24; hc++) {
    u16* B1w = (hc&1) ? W1b1 : W1b0;
    u16* B2w = (hc&1) ? W2b1 : W2b0;
    // fc1: 2 col tiles x 6 k, B from B1w; tanh-GELU sigmoid form -> Hs (wave-private rows)
    #pragma unroll
    for (int ct=0; ct<2; ct++) {
      f32x4 a1 = {0.f,0.f,0.f,0.f};
      const u16* wr = B1w + (ct*16+l15)*192;
      #pragma unroll
      for (int k0=0;k0<6;k0++) a1 = MFMA(af[k0], *(const short8*)(wr + (((k0*4+lg)^(l15&7))*8)), a1);
      float bb = b1[hc*32 + ct*16 + l15];
      #pragma unroll
      for (int i=0;i<4;i++){
        float v = a1[i] + bb;
        float t = v*v;
        float m = fmaf(t, GB, GA);
        float e = __expf(v*m);
        float hgl = v*__builtin_amdgcn_rcpf(1.f + e);
        Hs[(r0 + 4*lg + i)*40 + ct*16 + l15] = f2bf(hgl);
      }
    }
    // fc2: A = Hs own rows (32 k), B from B2w (row stride 32 u16); accumulate
    {
      short8 ah = *(const short8*)(Hs + (r0+l15)*40 + 8*lg);
      #pragma unroll
      for (int ct2=0; ct2<12; ct2++) {
        const u16* wr2 = B2w + (ct2*16+l15)*32 + ((lg ^ (l15&3))*8);
        acc2[ct2] = MFMA(ah, *(const short8*)(wr2), acc2[ct2]);
      }
    }
    __syncthreads();   // frees this iteration's buffers; drains loads issued last iter
    // prefetch hc+2 into the buffers just freed
    if (hc < 22) {
      const u16* s1 = W1f + (size_t)(hc+2)*6144;
      const u16* s2 = W2f + (size_t)(hc+2)*6144;
      u16* d1 = (hc&1) ? W1b1 : W1b0;
      u16* d2 = (hc&1) ? W2b1 : W2b0;
      gl_lds16(s1 + (size_t)tid*8, d1 + tid*8);
      if (tid < 256) gl_lds16(s1 + (size_t)(512+tid)*8, d1 + (512+tid)*8);
      gl_lds16(s2 + (size_t)tid*8, d2 + tid*8);
      if (tid < 256) gl_lds16(s2 + (size_t)(512+tid)*8, d2 + (512+tid)*8);
    }
  }
  #pragma unroll
  for (int ct2=0; ct2<12; ct2++) {
    int col = ct2*16+l15;
    float bb = b2[col];
    #pragma unroll
    for (int i=0;i<4;i++){
      size_t o = (rbase + r0 + 4*lg + i)*DIM + col;
      out[o] = out[o] + acc2[ct2][i] + bb;
    }
  }
}

// ---------------- launcher ----------------
extern "C" void kernel_launch(void* const* d_in, const int* in_sizes, int n_in,
                              void* d_out, int out_size, void* d_ws, size_t ws_size,
                              hipStream_t stream) {
  const float* x    = (const float*)d_in[0];
  const float* n1g  = (const float*)d_in[1];
  const float* n1b  = (const float*)d_in[2];
  const float* qkvw = (const float*)d_in[3];
  const float* qkvb = (const float*)d_in[4];
  const float* eb   = (const float*)d_in[5];
  const float* projw= (const float*)d_in[6];
  const float* projb= (const float*)d_in[7];
  const float* n2g  = (const float*)d_in[8];
  const float* n2b  = (const float*)d_in[9];
  const float* fc1w = (const float*)d_in[10];
  const float* fc1b = (const float*)d_in[11];
  const float* fc2w = (const float*)d_in[12];
  const float* fc2b = (const float*)d_in[13];
  float* out = (float*)d_out;
  char* ws = (char*)d_ws;

  u16* A   = (u16*)(ws);                 // 53,084,160 B  (LN1 out; later LN2 out Y)
  u16* AT  = (u16*)(ws + 53084160);      // 53,084,160 B
  u16* Wq  = (u16*)(ws + 106168320);     // qkv_w_t   221,184 B
  u16* Pw  = (u16*)(ws + 106389504);     // proj_w_t   73,728 B
  u16* W1f = (u16*)(ws + 106463232);     // fc1 frag-major 294,912 B
  u16* W2f = (u16*)(ws + 106758144);     // fc2 frag-major 294,912 B
  u16* Bexp = (u16*)d_out;               // 15.9 MB, dead once proj runs

  hipFuncSetAttribute((const void*)attn_kernel,     hipFuncAttributeMaxDynamicSharedMemorySize, SMEM3);
  hipFuncSetAttribute((const void*)proj_ln2_kernel, hipFuncAttributeMaxDynamicSharedMemorySize, SMEMP);
  hipFuncSetAttribute((const void*)mlp_kernel,      hipFuncAttributeMaxDynamicSharedMemorySize, SMEM5);

  transpose_bf16_kernel<<<432, 256, 0, stream>>>(qkvw, Wq, 192, 576);
  transpose_bf16_kernel<<<144, 256, 0, stream>>>(projw, Pw, 192, 192);
  pf_w1_kernel<<<576, 256, 0, stream>>>(fc1w, W1f);
  pf_w2_kernel<<<576, 256, 0, stream>>>(fc2w, W2f);
  bias_expand_kernel<<<384, 256, 0, stream>>>(eb, Bexp);
  ln1_window_kernel<<<34560, 256, 0, stream>>>(x, n1g, n1b, A);
  attn_kernel<<<5760, 576, SMEM3, stream>>>(A, Wq, qkvb, Bexp, AT);
  proj_ln2_kernel<<<1080, 512, SMEMP, stream>>>(AT, Pw, projb, x, n2g, n2b, out, A);
  mlp_kernel<<<1080, 512, SMEM5, stream>>>(A, W1f, fc1b, W2f, fc2b, out);
}